// Round 1
// baseline (920.726 us; speedup 1.0000x reference)
//
#include <hip/hip_runtime.h>
#include <math.h>

constexpr int NB = 2;           // batch
constexpr int IMG = 64;         // H == W
constexpr int CH = 128;         // channels (CIN == CI)
constexpr int NT = IMG * IMG;   // 4096 tokens per batch
constexpr int KSPLIT = 4;
constexpr int KEYS_PER_SPLIT = NT / KSPLIT;  // 1024

__device__ __forceinline__ float fcomp(float4 v, int q) {
  return q == 0 ? v.x : q == 1 ? v.y : q == 2 ? v.z : v.w;
}

// ---------------------------------------------------------------- mask value
// reference: m = resize(mask) (identity); m = where(m>0, 0, m); m = 1-m;
//            m *= resize(1-mask) (identity)  => mv = (1-(mask>0?0:mask))*(1-mask)
__global__ void k_init(const float* __restrict__ mask, float* __restrict__ mv) {
  const int i = blockIdx.x * 256 + threadIdx.x;
  if (i < NB * NT) {
    float mk = mask[i];
    float mm = mk > 0.f ? 0.f : mk;
    mv[i] = (1.f - mm) * (1.f - mk);
  }
}

// ---------------------------------------------------------------- GEMM M x 128 @ 128 x 128
// out[row, :] = (in[row, :] @ wmat + bias) * (mv ? mv[row] : 1)
__global__ __launch_bounds__(256) void k_gemm128(
    const float* __restrict__ in, const float* __restrict__ wmat,
    const float* __restrict__ bias, const float* __restrict__ mv,
    float* __restrict__ out) {
  __shared__ float Xs[64][132];
  __shared__ float Ws[128][128];
  const int t = threadIdx.x;
  const int r0 = blockIdx.x * 64;

  for (int i = t; i < 64 * 32; i += 256) {
    int row = i >> 5, c = (i & 31) << 2;
    *(float4*)&Xs[row][c] = *(const float4*)(in + (size_t)(r0 + row) * CH + c);
  }
  for (int i = t; i < 128 * 32; i += 256) {
    int row = i >> 5, c = (i & 31) << 2;
    *(float4*)&Ws[row][c] = *(const float4*)(wmat + (size_t)row * CH + c);
  }
  __syncthreads();

  const int rh = t >> 4, jh = t & 15;
  float acc[4][8];
#pragma unroll
  for (int i = 0; i < 4; ++i)
#pragma unroll
    for (int j = 0; j < 8; ++j) acc[i][j] = 0.f;

#pragma unroll 4
  for (int k = 0; k < CH; k += 4) {
    float4 a4[4];
#pragma unroll
    for (int i = 0; i < 4; ++i) a4[i] = *(const float4*)&Xs[rh + 16 * i][k];
#pragma unroll
    for (int kk = 0; kk < 4; ++kk) {
      float4 w0 = *(const float4*)&Ws[k + kk][jh * 8];
      float4 w1 = *(const float4*)&Ws[k + kk][jh * 8 + 4];
      float wv[8] = {w0.x, w0.y, w0.z, w0.w, w1.x, w1.y, w1.z, w1.w};
#pragma unroll
      for (int i = 0; i < 4; ++i) {
        float av = fcomp(a4[i], kk);
#pragma unroll
        for (int j = 0; j < 8; ++j) acc[i][j] = fmaf(av, wv[j], acc[i][j]);
      }
    }
  }

  float4 b0 = *(const float4*)(bias + jh * 8);
  float4 b1 = *(const float4*)(bias + jh * 8 + 4);
  float bv[8] = {b0.x, b0.y, b0.z, b0.w, b1.x, b1.y, b1.z, b1.w};
#pragma unroll
  for (int i = 0; i < 4; ++i) {
    int row = r0 + rh + 16 * i;
    float scale = mv ? mv[row] : 1.f;
    float4 o0 = make_float4((acc[i][0] + bv[0]) * scale, (acc[i][1] + bv[1]) * scale,
                            (acc[i][2] + bv[2]) * scale, (acc[i][3] + bv[3]) * scale);
    float4 o1 = make_float4((acc[i][4] + bv[4]) * scale, (acc[i][5] + bv[5]) * scale,
                            (acc[i][6] + bv[6]) * scale, (acc[i][7] + bv[7]) * scale);
    float* dst = out + (size_t)row * CH + jh * 8;
    *(float4*)dst = o0;
    *(float4*)(dst + 4) = o1;
  }
}

// ---------------------------------------------------------------- flash attention (fp32)
// partO[ks,b,n,c] = sum_{j in split ks} exp(theta_n . phi_j) * gxm[j,c]
// partL[ks,b,n]   = sum_{j in split ks} exp(theta_n . phi_j)      (unmasked denominator)
__global__ __launch_bounds__(256) void k_attn(
    const float* __restrict__ theta, const float* __restrict__ phi,
    const float* __restrict__ gxm, float* __restrict__ partO,
    float* __restrict__ partL) {
  __shared__ float Qs[64][132];
  __shared__ float Ks[32][132];
  __shared__ float Vs[32][132];
  __shared__ float Ps[64][36];

  const int t = threadIdx.x;
  const int bx = blockIdx.x;
  const int ks = bx & 3;
  const int qt = (bx >> 2) & 63;
  const int b = bx >> 8;
  const int q0 = qt * 64;
  const float* thB = theta + (size_t)b * NT * CH;
  const float* phB = phi + (size_t)b * NT * CH;
  const float* gxB = gxm + (size_t)b * NT * CH;

  for (int i = t; i < 64 * 32; i += 256) {
    int row = i >> 5, c = (i & 31) << 2;
    *(float4*)&Qs[row][c] = *(const float4*)(thB + (size_t)(q0 + row) * CH + c);
  }

  const int rh = t >> 4, jh = t & 15;
  float oacc[4][8];
#pragma unroll
  for (int i = 0; i < 4; ++i)
#pragma unroll
    for (int j = 0; j < 8; ++j) oacc[i][j] = 0.f;
  float lpart[4] = {0.f, 0.f, 0.f, 0.f};

  const int kbase = ks * KEYS_PER_SPLIT;
  for (int kt = 0; kt < KEYS_PER_SPLIT; kt += 32) {
    __syncthreads();  // previous PV done before K/V overwrite
    for (int i = t; i < 32 * 32; i += 256) {
      int row = i >> 5, c = (i & 31) << 2;
      size_t g = (size_t)(kbase + kt + row) * CH + c;
      *(float4*)&Ks[row][c] = *(const float4*)(phB + g);
      *(float4*)&Vs[row][c] = *(const float4*)(gxB + g);
    }
    __syncthreads();

    float s[4][2] = {{0.f, 0.f}, {0.f, 0.f}, {0.f, 0.f}, {0.f, 0.f}};
#pragma unroll 4
    for (int k = 0; k < CH; k += 4) {
      float4 a4[4], k4[2];
#pragma unroll
      for (int i = 0; i < 4; ++i) a4[i] = *(const float4*)&Qs[rh + 16 * i][k];
#pragma unroll
      for (int m = 0; m < 2; ++m) k4[m] = *(const float4*)&Ks[jh + 16 * m][k];
#pragma unroll
      for (int kk = 0; kk < 4; ++kk) {
#pragma unroll
        for (int i = 0; i < 4; ++i) {
          float av = fcomp(a4[i], kk);
#pragma unroll
          for (int m = 0; m < 2; ++m) s[i][m] = fmaf(av, fcomp(k4[m], kk), s[i][m]);
        }
      }
    }

#pragma unroll
    for (int i = 0; i < 4; ++i)
#pragma unroll
      for (int m = 0; m < 2; ++m) {
        float p = __expf(s[i][m]);
        lpart[i] += p;
        Ps[rh + 16 * i][jh + 16 * m] = p;
      }
    __syncthreads();

#pragma unroll 2
    for (int j = 0; j < 32; j += 4) {
      float4 pp[4];
#pragma unroll
      for (int i = 0; i < 4; ++i) pp[i] = *(const float4*)&Ps[rh + 16 * i][j];
#pragma unroll
      for (int jj = 0; jj < 4; ++jj) {
        float4 v0 = *(const float4*)&Vs[j + jj][jh * 8];
        float4 v1 = *(const float4*)&Vs[j + jj][jh * 8 + 4];
        float vv[8] = {v0.x, v0.y, v0.z, v0.w, v1.x, v1.y, v1.z, v1.w};
#pragma unroll
        for (int i = 0; i < 4; ++i) {
          float pv = fcomp(pp[i], jj);
#pragma unroll
          for (int c = 0; c < 8; ++c) oacc[i][c] = fmaf(pv, vv[c], oacc[i][c]);
        }
      }
    }
  }

  // reduce l over the 16 lanes (jh) that share each row group; groups are
  // 16 consecutive lanes -> xor shuffles stay inside the group
#pragma unroll
  for (int off = 1; off < 16; off <<= 1)
#pragma unroll
    for (int i = 0; i < 4; ++i) lpart[i] += __shfl_xor(lpart[i], off);

  const size_t obase = (size_t)(ks * NB + b) * NT;
#pragma unroll
  for (int i = 0; i < 4; ++i) {
    int grow = q0 + rh + 16 * i;
    float4 o0 = make_float4(oacc[i][0], oacc[i][1], oacc[i][2], oacc[i][3]);
    float4 o1 = make_float4(oacc[i][4], oacc[i][5], oacc[i][6], oacc[i][7]);
    float* dst = partO + (obase + grow) * CH + jh * 8;
    *(float4*)dst = o0;
    *(float4*)(dst + 4) = o1;
    if (jh == 0) partL[obase + grow] = lpart[i];
  }
}

// ---------------------------------------------------------------- combine ksplit partials
__global__ void k_attn_combine(const float* __restrict__ partO,
                               const float* __restrict__ partL,
                               float* __restrict__ y) {
  const int idx = blockIdx.x * 256 + threadIdx.x;  // float4 index, NB*NT*32 total
  const int c = (idx & 31) << 2;
  const size_t rowg = (size_t)(idx >> 5);
  float4 acc = make_float4(0.f, 0.f, 0.f, 0.f);
  float l = 0.f;
#pragma unroll
  for (int ksp = 0; ksp < KSPLIT; ++ksp) {
    const float4 p = *(const float4*)(partO + ((size_t)ksp * NB * NT + rowg) * CH + c);
    acc.x += p.x; acc.y += p.y; acc.z += p.z; acc.w += p.w;
    l += partL[(size_t)ksp * NB * NT + rowg];
  }
  const float inv = 1.f / l;
  acc.x *= inv; acc.y *= inv; acc.z *= inv; acc.w *= inv;
  *(float4*)(y + rowg * CH + c) = acc;
}

// ---------------------------------------------------------------- 3x3 reflect conv
// If AFFINE: input is first mapped through relu(a[ch]*v + b[ch]) where a,b come
// from instance-norm stats of the *input* tensor (conv1 output of the block).
template <bool AFFINE>
__global__ __launch_bounds__(256) void k_conv3x3(
    const float* __restrict__ in, const float* __restrict__ w,
    const float* __restrict__ cbias, const float* __restrict__ stats,
    const float* __restrict__ gamma, const float* __restrict__ beta,
    float* __restrict__ out) {
  __shared__ float Ins[6][10][132];
  __shared__ float Wc[9][8][128];
  __shared__ float Aff[2][128];

  const int t = threadIdx.x;
  const int bx = blockIdx.x;
  const int b = bx >> 7;
  const int rem = bx & 127;
  const int y0 = (rem >> 3) * 4;
  const int x0 = (rem & 7) * 8;

  if (AFFINE) {
    if (t < 128) {
      const float* st = stats + b * 256;
      float mean = st[t * 2] * (1.f / 4096.f);
      float var = st[t * 2 + 1] * (1.f / 4096.f) - mean * mean;
      float a = gamma[t] * rsqrtf(var + 1e-3f);
      Aff[0][t] = a;
      Aff[1][t] = beta[t] - mean * a;
    }
    __syncthreads();
  }

  const float* inB = in + (size_t)b * NT * CH;
  for (int i = t; i < 60 * 32; i += 256) {
    int pix = i >> 5, c = (i & 31) << 2;
    int r = pix / 10, cc = pix - r * 10;
    int iy = y0 - 1 + r;
    iy = iy < 0 ? 1 : (iy > 63 ? 62 : iy);   // reflect pad
    int ix = x0 - 1 + cc;
    ix = ix < 0 ? 1 : (ix > 63 ? 62 : ix);
    float4 v = *(const float4*)(inB + ((size_t)iy * IMG + ix) * CH + c);
    if (AFFINE) {
      v.x = fmaxf(0.f, fmaf(Aff[0][c + 0], v.x, Aff[1][c + 0]));
      v.y = fmaxf(0.f, fmaf(Aff[0][c + 1], v.y, Aff[1][c + 1]));
      v.z = fmaxf(0.f, fmaf(Aff[0][c + 2], v.z, Aff[1][c + 2]));
      v.w = fmaxf(0.f, fmaf(Aff[0][c + 3], v.w, Aff[1][c + 3]));
    }
    *(float4*)&Ins[r][cc][c] = v;
  }

  const int co_g = t & 15;
  const int sp = t >> 4;
  const int sy0 = sp >> 3;  // 0..1 ; second pixel uses sy0+2
  const int sx = sp & 7;
  float acc[2][8];
#pragma unroll
  for (int s = 0; s < 2; ++s)
#pragma unroll
    for (int c = 0; c < 8; ++c) acc[s][c] = 0.f;

  for (int cc0 = 0; cc0 < CH; cc0 += 8) {
    __syncthreads();
    for (int i = t; i < 9 * 8 * 32; i += 256) {
      int c = (i & 31) << 2;
      int rest = i >> 5;  // tap*8 + ci
      int ci = rest & 7, tap = rest >> 3;
      *(float4*)&Wc[tap][ci][c] =
          *(const float4*)(w + ((size_t)tap * CH + cc0 + ci) * CH + c);
    }
    __syncthreads();

#pragma unroll
    for (int tap = 0; tap < 9; ++tap) {
      const int dy = tap / 3, dx = tap % 3;
#pragma unroll
      for (int c0 = 0; c0 < 8; c0 += 4) {
        float4 in0 = *(const float4*)&Ins[sy0 + dy][sx + dx][cc0 + c0];
        float4 in1 = *(const float4*)&Ins[sy0 + 2 + dy][sx + dx][cc0 + c0];
#pragma unroll
        for (int q = 0; q < 4; ++q) {
          float4 w0 = *(const float4*)&Wc[tap][c0 + q][co_g * 8];
          float4 w1 = *(const float4*)&Wc[tap][c0 + q][co_g * 8 + 4];
          float wv[8] = {w0.x, w0.y, w0.z, w0.w, w1.x, w1.y, w1.z, w1.w};
          float i0 = fcomp(in0, q), i1 = fcomp(in1, q);
#pragma unroll
          for (int c = 0; c < 8; ++c) {
            acc[0][c] = fmaf(i0, wv[c], acc[0][c]);
            acc[1][c] = fmaf(i1, wv[c], acc[1][c]);
          }
        }
      }
    }
  }

  float4 b0 = *(const float4*)(cbias + co_g * 8);
  float4 b1 = *(const float4*)(cbias + co_g * 8 + 4);
  float bv[8] = {b0.x, b0.y, b0.z, b0.w, b1.x, b1.y, b1.z, b1.w};
#pragma unroll
  for (int s = 0; s < 2; ++s) {
    int yy = y0 + sy0 + 2 * s;
    int xx = x0 + sx;
    float* dst = out + (((size_t)b * IMG + yy) * IMG + xx) * CH + co_g * 8;
    float4 o0 = make_float4(acc[s][0] + bv[0], acc[s][1] + bv[1],
                            acc[s][2] + bv[2], acc[s][3] + bv[3]);
    float4 o1 = make_float4(acc[s][4] + bv[4], acc[s][5] + bv[5],
                            acc[s][6] + bv[6], acc[s][7] + bv[7]);
    *(float4*)dst = o0;
    *(float4*)(dst + 4) = o1;
  }
}

// ---------------------------------------------------------------- instance-norm stats
// pass 1: per-128-pixel-block partial sum/sumsq per channel (deterministic, no atomics)
__global__ void k_instats(const float* __restrict__ xin, float* __restrict__ part) {
  __shared__ float red[2][256];
  const int t = threadIdx.x;
  const int bx = blockIdx.x;  // NB*32 blocks, 128 pixels each
  const size_t base = (size_t)bx * 16384;
  float s = 0.f, sq = 0.f;
  for (int k = 0; k < 64; ++k) {
    float v = xin[base + t + 256 * k];  // channel = t & 127 (constant per thread)
    s += v;
    sq = fmaf(v, v, sq);
  }
  red[0][t] = s;
  red[1][t] = sq;
  __syncthreads();
  if (t < 128) {
    float ssum = red[0][t] + red[0][t + 128];
    float qsum = red[1][t] + red[1][t + 128];
    part[(size_t)bx * 256 + t * 2] = ssum;
    part[(size_t)bx * 256 + t * 2 + 1] = qsum;
  }
}

// pass 2: reduce 32 partials per batch -> stats[b*256 + ch*2 + {0,1}]
__global__ void k_statsreduce(const float* __restrict__ part, float* __restrict__ st) {
  const int b = blockIdx.x;
  const int t = threadIdx.x;
  float acc = 0.f;
  for (int k = 0; k < 32; ++k) acc += part[(size_t)(b * 32 + k) * 256 + t];
  st[b * 256 + t] = acc;
}

// ---------------------------------------------------------------- residual: wy += IN(c2)
__global__ void k_residual(const float* __restrict__ c2v, const float* __restrict__ st,
                           const float* __restrict__ gamma,
                           const float* __restrict__ beta, float* __restrict__ wy) {
  const int idx = blockIdx.x * 256 + threadIdx.x;  // float4 index
  const int c = (idx & 31) << 2;
  const int b = idx >> 17;  // 131072 float4 per batch
  const float* stb = st + b * 256;
  const float4 v = ((const float4*)c2v)[idx];
  float4 wv = ((float4*)wy)[idx];
  float vv[4] = {v.x, v.y, v.z, v.w};
  float wvv[4] = {wv.x, wv.y, wv.z, wv.w};
#pragma unroll
  for (int q = 0; q < 4; ++q) {
    int ch = c + q;
    float mean = stb[ch * 2] * (1.f / 4096.f);
    float var = stb[ch * 2 + 1] * (1.f / 4096.f) - mean * mean;
    float a = gamma[ch] * rsqrtf(var + 1e-3f);
    float bb = beta[ch] - mean * a;
    wvv[q] += fmaf(a, vv[q], bb);
  }
  ((float4*)wy)[idx] = make_float4(wvv[0], wvv[1], wvv[2], wvv[3]);
}

// ---------------------------------------------------------------- final blend
__global__ void k_final(const float* __restrict__ x, const float* __restrict__ wy,
                        const float* __restrict__ mv, float* __restrict__ out) {
  const int idx = blockIdx.x * 256 + threadIdx.x;  // float4 index
  const float m = mv[idx >> 5];
  const float4 xv = ((const float4*)x)[idx];
  const float4 wv = ((const float4*)wy)[idx];
  float4 o;
  o.x = m * xv.x + (1.f - m) * wv.x;
  o.y = m * xv.y + (1.f - m) * wv.y;
  o.z = m * xv.z + (1.f - m) * wv.z;
  o.w = m * xv.w + (1.f - m) * wv.w;
  ((float4*)out)[idx] = o;
}

// ================================================================ launch
extern "C" void kernel_launch(void* const* d_in, const int* in_sizes, int n_in,
                              void* d_out, int out_size, void* d_ws, size_t ws_size,
                              hipStream_t stream) {
  (void)in_sizes; (void)n_in; (void)out_size; (void)ws_size;
  const float* x    = (const float*)d_in[0];
  const float* mask = (const float*)d_in[1];
  const float* wg   = (const float*)d_in[2];
  const float* bg   = (const float*)d_in[3];
  const float* wt   = (const float*)d_in[4];
  const float* bt   = (const float*)d_in[5];
  const float* wp   = (const float*)d_in[6];
  const float* bp   = (const float*)d_in[7];
  const float* ww   = (const float*)d_in[8];
  const float* bw   = (const float*)d_in[9];
  const float* rw1  = (const float*)d_in[10];
  const float* rb1  = (const float*)d_in[11];
  const float* rg1  = (const float*)d_in[12];
  const float* rbe1 = (const float*)d_in[13];
  const float* rw2  = (const float*)d_in[14];
  const float* rb2  = (const float*)d_in[15];
  const float* rg2  = (const float*)d_in[16];
  const float* rbe2 = (const float*)d_in[17];
  float* out = (float*)d_out;

  float* W = (float*)d_ws;
  float* mv    = W;                    // 8192
  float* stats = W + 8192;             // 6 regions * 512 = 3072
  float* theta = W + 11264;            // 1048576 (aliased as y after attention)
  float* phi   = theta + 1048576;      // 1048576 (aliased as c1 after attention)
  float* gxm   = phi + 1048576;        // 1048576 (aliased as c2 after attention)
  float* wy    = gxm + 1048576;        // 1048576
  float* partO = wy + 1048576;         // 4194304
  float* partL = partO + 4194304;      // 32768
  float* spart = partL + 32768;        // 16384 (stats partials, reused per conv)
  float* y = theta;
  float* c1 = phi;
  float* c2 = gxm;

  k_init<<<32, 256, 0, stream>>>(mask, mv);
  k_gemm128<<<128, 256, 0, stream>>>(x, wt, bt, nullptr, theta);
  k_gemm128<<<128, 256, 0, stream>>>(x, wp, bp, nullptr, phi);
  k_gemm128<<<128, 256, 0, stream>>>(x, wg, bg, mv, gxm);  // g_x * m folded into V
  k_attn<<<512, 256, 0, stream>>>(theta, phi, gxm, partO, partL);
  k_attn_combine<<<1024, 256, 0, stream>>>(partO, partL, y);
  k_gemm128<<<128, 256, 0, stream>>>(y, ww, bw, nullptr, wy);

  for (int i = 0; i < 3; ++i) {
    float* st1 = stats + (2 * i) * 512;
    float* st2 = stats + (2 * i + 1) * 512;
    k_conv3x3<false><<<256, 256, 0, stream>>>(wy, rw1 + (size_t)i * 147456,
                                              rb1 + i * 128, nullptr, nullptr,
                                              nullptr, c1);
    k_instats<<<64, 256, 0, stream>>>(c1, spart);
    k_statsreduce<<<NB, 256, 0, stream>>>(spart, st1);
    k_conv3x3<true><<<256, 256, 0, stream>>>(c1, rw2 + (size_t)i * 147456,
                                             rb2 + i * 128, st1, rg1 + i * 128,
                                             rbe1 + i * 128, c2);
    k_instats<<<64, 256, 0, stream>>>(c2, spart);
    k_statsreduce<<<NB, 256, 0, stream>>>(spart, st2);
    k_residual<<<1024, 256, 0, stream>>>(c2, st2, rg2 + i * 128, rbe2 + i * 128, wy);
  }

  k_final<<<1024, 256, 0, stream>>>(x, wy, mv, out);
}

// Round 2
// 684.191 us; speedup vs baseline: 1.3457x; 1.3457x over previous
//
#include <hip/hip_runtime.h>
#include <math.h>

constexpr int NB = 2;           // batch
constexpr int IMG = 64;         // H == W
constexpr int CH = 128;         // channels (CIN == CI)
constexpr int NT = IMG * IMG;   // 4096 tokens per batch
constexpr int ATT_KSPLIT = 8;
constexpr int KPS = NT / ATT_KSPLIT;  // 512 keys per split

typedef __bf16 bf16x8 __attribute__((ext_vector_type(8)));
typedef float f32x4 __attribute__((ext_vector_type(4)));

__device__ __forceinline__ float fcomp(float4 v, int q) {
  return q == 0 ? v.x : q == 1 ? v.y : q == 2 ? v.z : v.w;
}

__device__ __forceinline__ unsigned f2bf(float x) {  // RNE float->bf16 bits
  unsigned u = __float_as_uint(x);
  return (u + 0x7fffu + ((u >> 16) & 1u)) >> 16;
}
__device__ __forceinline__ float bf2f(unsigned h) {
  return __uint_as_float(h << 16);
}

// ---------------------------------------------------------------- mask value
// mv = (1-(mask>0?0:mask))*(1-mask)
__global__ void k_init(const float* __restrict__ mask, float* __restrict__ mv) {
  const int i = blockIdx.x * 256 + threadIdx.x;
  if (i < NB * NT) {
    float mk = mask[i];
    float mm = mk > 0.f ? 0.f : mk;
    mv[i] = (1.f - mm) * (1.f - mk);
  }
}

// ---------------------------------------------------------------- GEMM M x 128 @ 128 x 128
// OM: 0 = f32 out, 1 = bf16 out, 2 = bf16 out scaled by mv[row]
template <int OM>
__global__ __launch_bounds__(256) void k_gemm128(
    const float* __restrict__ in, const float* __restrict__ wmat,
    const float* __restrict__ bias, const float* __restrict__ mv,
    void* __restrict__ outv) {
  __shared__ float Xs[64][132];
  __shared__ float Ws[128][128];
  const int t = threadIdx.x;
  const int r0 = blockIdx.x * 64;

  for (int i = t; i < 64 * 32; i += 256) {
    int row = i >> 5, c = (i & 31) << 2;
    *(float4*)&Xs[row][c] = *(const float4*)(in + (size_t)(r0 + row) * CH + c);
  }
  for (int i = t; i < 128 * 32; i += 256) {
    int row = i >> 5, c = (i & 31) << 2;
    *(float4*)&Ws[row][c] = *(const float4*)(wmat + (size_t)row * CH + c);
  }
  __syncthreads();

  const int rh = t >> 4, jh = t & 15;
  float acc[4][8];
#pragma unroll
  for (int i = 0; i < 4; ++i)
#pragma unroll
    for (int j = 0; j < 8; ++j) acc[i][j] = 0.f;

#pragma unroll 4
  for (int k = 0; k < CH; k += 4) {
    float4 a4[4];
#pragma unroll
    for (int i = 0; i < 4; ++i) a4[i] = *(const float4*)&Xs[rh + 16 * i][k];
#pragma unroll
    for (int kk = 0; kk < 4; ++kk) {
      float4 w0 = *(const float4*)&Ws[k + kk][jh * 8];
      float4 w1 = *(const float4*)&Ws[k + kk][jh * 8 + 4];
      float wv[8] = {w0.x, w0.y, w0.z, w0.w, w1.x, w1.y, w1.z, w1.w};
#pragma unroll
      for (int i = 0; i < 4; ++i) {
        float av = fcomp(a4[i], kk);
#pragma unroll
        for (int j = 0; j < 8; ++j) acc[i][j] = fmaf(av, wv[j], acc[i][j]);
      }
    }
  }

  float4 b0 = *(const float4*)(bias + jh * 8);
  float4 b1 = *(const float4*)(bias + jh * 8 + 4);
  float bv[8] = {b0.x, b0.y, b0.z, b0.w, b1.x, b1.y, b1.z, b1.w};
#pragma unroll
  for (int i = 0; i < 4; ++i) {
    int row = r0 + rh + 16 * i;
    float scale = 1.f;
    if constexpr (OM == 2) scale = mv[row];
    float o[8];
#pragma unroll
    for (int j = 0; j < 8; ++j) o[j] = (acc[i][j] + bv[j]) * scale;
    if constexpr (OM == 0) {
      float* outf = (float*)outv;
      float* dst = outf + (size_t)row * CH + jh * 8;
      *(float4*)dst = make_float4(o[0], o[1], o[2], o[3]);
      *(float4*)(dst + 4) = make_float4(o[4], o[5], o[6], o[7]);
    } else {
      unsigned short* outb = (unsigned short*)outv;
      uint4 pk;
      pk.x = f2bf(o[0]) | (f2bf(o[1]) << 16);
      pk.y = f2bf(o[2]) | (f2bf(o[3]) << 16);
      pk.z = f2bf(o[4]) | (f2bf(o[5]) << 16);
      pk.w = f2bf(o[6]) | (f2bf(o[7]) << 16);
      *(uint4*)(outb + (size_t)row * CH + jh * 8) = pk;
    }
  }
}

// ---------------------------------------------------------------- transpose V: [b][key][c] -> [b][c][key]
__global__ __launch_bounds__(256) void k_transpose(
    const unsigned short* __restrict__ src, unsigned short* __restrict__ vt) {
  __shared__ __align__(16) unsigned short T[64][136];
  const int t = threadIdx.x;
  const int bx = blockIdx.x;
  const int b = bx >> 6;
  const int key0 = (bx & 63) * 64;
  const unsigned short* s = src + ((size_t)b * NT + key0) * CH;
#pragma unroll
  for (int i = 0; i < 4; ++i) {
    int idx = t + 256 * i;
    int row = idx >> 4, c8 = (idx & 15) * 8;
    *(uint4*)&T[row][c8] = *(const uint4*)(s + (size_t)row * CH + c8);
  }
  __syncthreads();
  const int c = t >> 1, h = t & 1;
  unsigned buf[16];
#pragma unroll
  for (int j = 0; j < 16; ++j)
    buf[j] = (unsigned)T[h * 32 + 2 * j][c] | ((unsigned)T[h * 32 + 2 * j + 1][c] << 16);
  unsigned short* dst = vt + ((size_t)b * CH + c) * NT + key0 + h * 32;
  uint4* d4 = (uint4*)dst;
#pragma unroll
  for (int q = 0; q < 4; ++q)
    d4[q] = make_uint4(buf[4 * q], buf[4 * q + 1], buf[4 * q + 2], buf[4 * q + 3]);
}

// ---------------------------------------------------------------- flash attention (bf16 MFMA)
// 4 waves x 32 q-rows, KBLK=64, 8 key-tiles per block (KSPLIT=8).
// partO[ks][b][n][c] (bf16) = sum_j exp(S) * Vm[j][c];  partL = sum_j exp(S)
__global__ __launch_bounds__(256, 2) void k_attn(
    const unsigned short* __restrict__ theta, const unsigned short* __restrict__ phi,
    const unsigned short* __restrict__ vt, unsigned short* __restrict__ partO,
    float* __restrict__ partL) {
  __shared__ __align__(16) unsigned short Klds[64][136];   // [key][c] +8 pad
  __shared__ __align__(16) unsigned short Vtlds[128][72];  // [c][key] +8 pad
  __shared__ __align__(16) unsigned short Plds[4][32][72]; // per-wave P

  const int t = threadIdx.x;
  const int bx = blockIdx.x;
  const int ks = bx & 7;
  const int qt = (bx >> 3) & 31;
  const int b = bx >> 8;
  const int w = t >> 6;
  const int lane = t & 63;
  const int lg = lane >> 4;
  const int lc = lane & 15;
  const int q0 = qt * 128 + w * 32;

  const unsigned short* thB = theta + (size_t)b * NT * CH;
  const unsigned short* phB = phi + (size_t)b * NT * CH;
  const unsigned short* vtB = vt + (size_t)b * CH * NT;

  // Q fragments held in registers: A[row=lc][k=lg*8+j]
  bf16x8 qf[2][4];
#pragma unroll
  for (int q2 = 0; q2 < 2; ++q2)
#pragma unroll
    for (int k = 0; k < 4; ++k)
      qf[q2][k] = *(const bf16x8*)(thB + (size_t)(q0 + q2 * 16 + lc) * CH + k * 32 + lg * 8);

  f32x4 oacc[2][8];
#pragma unroll
  for (int q2 = 0; q2 < 2; ++q2)
#pragma unroll
    for (int c = 0; c < 8; ++c)
#pragma unroll
      for (int r = 0; r < 4; ++r) oacc[q2][c][r] = 0.f;
  float lsum[2][4] = {{0.f, 0.f, 0.f, 0.f}, {0.f, 0.f, 0.f, 0.f}};

  for (int kt = 0; kt < KPS; kt += 64) {
    const int key0 = ks * KPS + kt;
    __syncthreads();  // previous tile's LDS reads done
#pragma unroll
    for (int i = 0; i < 4; ++i) {
      int idx = t + 256 * i;
      int row = idx >> 4, c8 = (idx & 15) * 8;
      *(uint4*)&Klds[row][c8] = *(const uint4*)(phB + (size_t)(key0 + row) * CH + c8);
      int rowv = idx >> 3, k8 = (idx & 7) * 8;
      *(uint4*)&Vtlds[rowv][k8] = *(const uint4*)(vtB + (size_t)rowv * NT + key0 + k8);
    }
    __syncthreads();

    // QK^T: S[q][key] tiles; B[k=c][col=key] frag = Klds[key][c] contiguous
#pragma unroll
    for (int col = 0; col < 4; ++col) {
      bf16x8 kf[4];
#pragma unroll
      for (int k = 0; k < 4; ++k)
        kf[k] = *(const bf16x8*)&Klds[col * 16 + lc][k * 32 + lg * 8];
      f32x4 s0, s1;
#pragma unroll
      for (int r = 0; r < 4; ++r) { s0[r] = 0.f; s1[r] = 0.f; }
#pragma unroll
      for (int k = 0; k < 4; ++k) {
        s0 = __builtin_amdgcn_mfma_f32_16x16x32_bf16(qf[0][k], kf[k], s0, 0, 0, 0);
        s1 = __builtin_amdgcn_mfma_f32_16x16x32_bf16(qf[1][k], kf[k], s1, 0, 0, 0);
      }
      // exp + stash P (D layout: row = lg*4+r, col = lc)
#pragma unroll
      for (int r = 0; r < 4; ++r) {
        float p0 = __expf(s0[r]);
        lsum[0][r] += p0;
        Plds[w][lg * 4 + r][col * 16 + lc] = (unsigned short)f2bf(p0);
        float p1 = __expf(s1[r]);
        lsum[1][r] += p1;
        Plds[w][16 + lg * 4 + r][col * 16 + lc] = (unsigned short)f2bf(p1);
      }
    }

    // PV: A[row=q(lc)][k=key], B[k=key][col=c(lc)] = Vt[c][key] contiguous
#pragma unroll
    for (int kp = 0; kp < 2; ++kp) {
      bf16x8 pa0 = *(const bf16x8*)&Plds[w][lc][kp * 32 + lg * 8];
      bf16x8 pa1 = *(const bf16x8*)&Plds[w][16 + lc][kp * 32 + lg * 8];
#pragma unroll
      for (int col = 0; col < 8; ++col) {
        bf16x8 vf = *(const bf16x8*)&Vtlds[col * 16 + lc][kp * 32 + lg * 8];
        oacc[0][col] = __builtin_amdgcn_mfma_f32_16x16x32_bf16(pa0, vf, oacc[0][col], 0, 0, 0);
        oacc[1][col] = __builtin_amdgcn_mfma_f32_16x16x32_bf16(pa1, vf, oacc[1][col], 0, 0, 0);
      }
    }
  }

  // reduce lsum across the 16 lanes (lc) sharing each row group
#pragma unroll
  for (int off = 1; off < 16; off <<= 1)
#pragma unroll
    for (int q2 = 0; q2 < 2; ++q2)
#pragma unroll
      for (int r = 0; r < 4; ++r) lsum[q2][r] += __shfl_xor(lsum[q2][r], off);

  const size_t obase = ((size_t)ks * NB + b) * NT;
#pragma unroll
  for (int q2 = 0; q2 < 2; ++q2) {
#pragma unroll
    for (int col = 0; col < 8; ++col)
#pragma unroll
      for (int r = 0; r < 4; ++r) {
        int row = q0 + q2 * 16 + lg * 4 + r;
        partO[(obase + row) * CH + col * 16 + lc] = (unsigned short)f2bf(oacc[q2][col][r]);
      }
    if (lc == 0) {
#pragma unroll
      for (int r = 0; r < 4; ++r)
        partL[obase + q0 + q2 * 16 + lg * 4 + r] = lsum[q2][r];
    }
  }
}

// ---------------------------------------------------------------- combine ksplit partials
__global__ void k_attn_combine(const unsigned short* __restrict__ partO,
                               const float* __restrict__ partL,
                               float* __restrict__ y) {
  const int idx = blockIdx.x * 256 + threadIdx.x;  // (B*N*CH)/4 threads
  const int c = (idx & 31) << 2;
  const size_t rowg = (size_t)(idx >> 5);
  float a0 = 0.f, a1 = 0.f, a2 = 0.f, a3 = 0.f, l = 0.f;
#pragma unroll
  for (int ksp = 0; ksp < ATT_KSPLIT; ++ksp) {
    const unsigned short* p = partO + ((size_t)ksp * NB * NT + rowg) * CH + c;
    uint2 u = *(const uint2*)p;
    a0 += bf2f(u.x & 0xffffu);
    a1 += bf2f(u.x >> 16);
    a2 += bf2f(u.y & 0xffffu);
    a3 += bf2f(u.y >> 16);
    l += partL[(size_t)ksp * NB * NT + rowg];
  }
  const float inv = 1.f / l;
  *(float4*)(y + rowg * CH + c) = make_float4(a0 * inv, a1 * inv, a2 * inv, a3 * inv);
}

// ---------------------------------------------------------------- 3x3 reflect conv (fp32)
template <bool AFFINE>
__global__ __launch_bounds__(256) void k_conv3x3(
    const float* __restrict__ in, const float* __restrict__ w,
    const float* __restrict__ cbias, const float* __restrict__ stats,
    const float* __restrict__ gamma, const float* __restrict__ beta,
    float* __restrict__ out) {
  __shared__ float Ins[6][10][132];
  __shared__ float Wc[9][8][128];
  __shared__ float Aff[2][128];

  const int t = threadIdx.x;
  const int bx = blockIdx.x;
  const int b = bx >> 7;
  const int rem = bx & 127;
  const int y0 = (rem >> 3) * 4;
  const int x0 = (rem & 7) * 8;

  if (AFFINE) {
    if (t < 128) {
      const float* st = stats + b * 256;
      float mean = st[t * 2] * (1.f / 4096.f);
      float var = st[t * 2 + 1] * (1.f / 4096.f) - mean * mean;
      float a = gamma[t] * rsqrtf(var + 1e-3f);
      Aff[0][t] = a;
      Aff[1][t] = beta[t] - mean * a;
    }
    __syncthreads();
  }

  const float* inB = in + (size_t)b * NT * CH;
  for (int i = t; i < 60 * 32; i += 256) {
    int pix = i >> 5, c = (i & 31) << 2;
    int r = pix / 10, cc = pix - r * 10;
    int iy = y0 - 1 + r;
    iy = iy < 0 ? 1 : (iy > 63 ? 62 : iy);
    int ix = x0 - 1 + cc;
    ix = ix < 0 ? 1 : (ix > 63 ? 62 : ix);
    float4 v = *(const float4*)(inB + ((size_t)iy * IMG + ix) * CH + c);
    if (AFFINE) {
      v.x = fmaxf(0.f, fmaf(Aff[0][c + 0], v.x, Aff[1][c + 0]));
      v.y = fmaxf(0.f, fmaf(Aff[0][c + 1], v.y, Aff[1][c + 1]));
      v.z = fmaxf(0.f, fmaf(Aff[0][c + 2], v.z, Aff[1][c + 2]));
      v.w = fmaxf(0.f, fmaf(Aff[0][c + 3], v.w, Aff[1][c + 3]));
    }
    *(float4*)&Ins[r][cc][c] = v;
  }

  const int co_g = t & 15;
  const int sp = t >> 4;
  const int sy0 = sp >> 3;
  const int sx = sp & 7;
  float acc[2][8];
#pragma unroll
  for (int s = 0; s < 2; ++s)
#pragma unroll
    for (int c = 0; c < 8; ++c) acc[s][c] = 0.f;

  for (int cc0 = 0; cc0 < CH; cc0 += 8) {
    __syncthreads();
    for (int i = t; i < 9 * 8 * 32; i += 256) {
      int c = (i & 31) << 2;
      int rest = i >> 5;
      int ci = rest & 7, tap = rest >> 3;
      *(float4*)&Wc[tap][ci][c] =
          *(const float4*)(w + ((size_t)tap * CH + cc0 + ci) * CH + c);
    }
    __syncthreads();

#pragma unroll
    for (int tap = 0; tap < 9; ++tap) {
      const int dy = tap / 3, dx = tap % 3;
#pragma unroll
      for (int c0 = 0; c0 < 8; c0 += 4) {
        float4 in0 = *(const float4*)&Ins[sy0 + dy][sx + dx][cc0 + c0];
        float4 in1 = *(const float4*)&Ins[sy0 + 2 + dy][sx + dx][cc0 + c0];
#pragma unroll
        for (int q = 0; q < 4; ++q) {
          float4 w0 = *(const float4*)&Wc[tap][c0 + q][co_g * 8];
          float4 w1 = *(const float4*)&Wc[tap][c0 + q][co_g * 8 + 4];
          float wv[8] = {w0.x, w0.y, w0.z, w0.w, w1.x, w1.y, w1.z, w1.w};
          float i0 = fcomp(in0, q), i1 = fcomp(in1, q);
#pragma unroll
          for (int c = 0; c < 8; ++c) {
            acc[0][c] = fmaf(i0, wv[c], acc[0][c]);
            acc[1][c] = fmaf(i1, wv[c], acc[1][c]);
          }
        }
      }
    }
  }

  float4 b0 = *(const float4*)(cbias + co_g * 8);
  float4 b1 = *(const float4*)(cbias + co_g * 8 + 4);
  float bv[8] = {b0.x, b0.y, b0.z, b0.w, b1.x, b1.y, b1.z, b1.w};
#pragma unroll
  for (int s = 0; s < 2; ++s) {
    int yy = y0 + sy0 + 2 * s;
    int xx = x0 + sx;
    float* dst = out + (((size_t)b * IMG + yy) * IMG + xx) * CH + co_g * 8;
    *(float4*)dst = make_float4(acc[s][0] + bv[0], acc[s][1] + bv[1],
                                acc[s][2] + bv[2], acc[s][3] + bv[3]);
    *(float4*)(dst + 4) = make_float4(acc[s][4] + bv[4], acc[s][5] + bv[5],
                                      acc[s][6] + bv[6], acc[s][7] + bv[7]);
  }
}

// ---------------------------------------------------------------- instance-norm stats
__global__ void k_instats(const float* __restrict__ xin, float* __restrict__ part) {
  __shared__ float red[2][256];
  const int t = threadIdx.x;
  const int bx = blockIdx.x;
  const size_t base = (size_t)bx * 16384;
  float s = 0.f, sq = 0.f;
  for (int k = 0; k < 64; ++k) {
    float v = xin[base + t + 256 * k];
    s += v;
    sq = fmaf(v, v, sq);
  }
  red[0][t] = s;
  red[1][t] = sq;
  __syncthreads();
  if (t < 128) {
    part[(size_t)bx * 256 + t * 2] = red[0][t] + red[0][t + 128];
    part[(size_t)bx * 256 + t * 2 + 1] = red[1][t] + red[1][t + 128];
  }
}

__global__ void k_statsreduce(const float* __restrict__ part, float* __restrict__ st) {
  const int b = blockIdx.x;
  const int t = threadIdx.x;
  float acc = 0.f;
  for (int k = 0; k < 32; ++k) acc += part[(size_t)(b * 32 + k) * 256 + t];
  st[b * 256 + t] = acc;
}

// ---------------------------------------------------------------- residual: wy += IN(c2)
__global__ void k_residual(const float* __restrict__ c2v, const float* __restrict__ st,
                           const float* __restrict__ gamma,
                           const float* __restrict__ beta, float* __restrict__ wy) {
  const int idx = blockIdx.x * 256 + threadIdx.x;
  const int c = (idx & 31) << 2;
  const int b = idx >> 17;
  const float* stb = st + b * 256;
  const float4 v = ((const float4*)c2v)[idx];
  float4 wv = ((float4*)wy)[idx];
  float vv[4] = {v.x, v.y, v.z, v.w};
  float wvv[4] = {wv.x, wv.y, wv.z, wv.w};
#pragma unroll
  for (int q = 0; q < 4; ++q) {
    int ch = c + q;
    float mean = stb[ch * 2] * (1.f / 4096.f);
    float var = stb[ch * 2 + 1] * (1.f / 4096.f) - mean * mean;
    float a = gamma[ch] * rsqrtf(var + 1e-3f);
    float bb = beta[ch] - mean * a;
    wvv[q] += fmaf(a, vv[q], bb);
  }
  ((float4*)wy)[idx] = make_float4(wvv[0], wvv[1], wvv[2], wvv[3]);
}

// ---------------------------------------------------------------- final blend
__global__ void k_final(const float* __restrict__ x, const float* __restrict__ wy,
                        const float* __restrict__ mv, float* __restrict__ out) {
  const int idx = blockIdx.x * 256 + threadIdx.x;
  const float m = mv[idx >> 5];
  const float4 xv = ((const float4*)x)[idx];
  const float4 wv = ((const float4*)wy)[idx];
  float4 o;
  o.x = m * xv.x + (1.f - m) * wv.x;
  o.y = m * xv.y + (1.f - m) * wv.y;
  o.z = m * xv.z + (1.f - m) * wv.z;
  o.w = m * xv.w + (1.f - m) * wv.w;
  ((float4*)out)[idx] = o;
}

// ================================================================ launch
extern "C" void kernel_launch(void* const* d_in, const int* in_sizes, int n_in,
                              void* d_out, int out_size, void* d_ws, size_t ws_size,
                              hipStream_t stream) {
  (void)in_sizes; (void)n_in; (void)out_size; (void)ws_size;
  const float* x    = (const float*)d_in[0];
  const float* mask = (const float*)d_in[1];
  const float* wg   = (const float*)d_in[2];
  const float* bg   = (const float*)d_in[3];
  const float* wt   = (const float*)d_in[4];
  const float* bt   = (const float*)d_in[5];
  const float* wp   = (const float*)d_in[6];
  const float* bp   = (const float*)d_in[7];
  const float* ww   = (const float*)d_in[8];
  const float* bw   = (const float*)d_in[9];
  const float* rw1  = (const float*)d_in[10];
  const float* rb1  = (const float*)d_in[11];
  const float* rg1  = (const float*)d_in[12];
  const float* rbe1 = (const float*)d_in[13];
  const float* rw2  = (const float*)d_in[14];
  const float* rb2  = (const float*)d_in[15];
  const float* rg2  = (const float*)d_in[16];
  const float* rbe2 = (const float*)d_in[17];
  float* out = (float*)d_out;

  char* W = (char*)d_ws;
  // live-range-aware layout (total 25.5 MB)
  float*          mv    = (float*)(W + 0);                      // 32 KB
  unsigned short* thb   = (unsigned short*)(W + 32768);         // 2 MB bf16
  unsigned short* phb   = (unsigned short*)(W + 32768 + 2097152);
  unsigned short* gxb   = (unsigned short*)(W + 32768 + 2 * 2097152);
  unsigned short* vtb   = (unsigned short*)(W + 32768 + 3 * 2097152);
  float*          partL = (float*)(W + 32768 + 4 * 2097152);    // 256 KB
  unsigned short* partO = (unsigned short*)(W + 32768 + 4 * 2097152 + 262144);  // 16 MB
  // aliases (dead regions reused after attention)
  float* y     = (float*)(W + 32768);                            // over thb+phb (4 MB)
  float* wy    = (float*)(W + 32768 + 2 * 2097152);              // over gxb+vtb (4 MB)
  float* c1    = (float*)partO;                                  // 4 MB
  float* c2    = (float*)((char*)partO + 4194304);               // 4 MB
  float* spart = (float*)((char*)partO + 8388608);               // 64 KB
  float* stats = (float*)((char*)partO + 8388608 + 65536);       // 12 KB

  k_init<<<32, 256, 0, stream>>>(mask, mv);
  k_gemm128<1><<<128, 256, 0, stream>>>(x, wt, bt, nullptr, thb);
  k_gemm128<1><<<128, 256, 0, stream>>>(x, wp, bp, nullptr, phb);
  k_gemm128<2><<<128, 256, 0, stream>>>(x, wg, bg, mv, gxb);  // mask folded into V
  k_transpose<<<128, 256, 0, stream>>>(gxb, vtb);
  k_attn<<<512, 256, 0, stream>>>(thb, phb, vtb, partO, partL);
  k_attn_combine<<<1024, 256, 0, stream>>>(partO, partL, y);
  k_gemm128<0><<<128, 256, 0, stream>>>(y, ww, bw, nullptr, wy);

  for (int i = 0; i < 3; ++i) {
    float* st1 = stats + (2 * i) * 512;
    float* st2 = stats + (2 * i + 1) * 512;
    k_conv3x3<false><<<256, 256, 0, stream>>>(wy, rw1 + (size_t)i * 147456,
                                              rb1 + i * 128, nullptr, nullptr,
                                              nullptr, c1);
    k_instats<<<64, 256, 0, stream>>>(c1, spart);
    k_statsreduce<<<NB, 256, 0, stream>>>(spart, st1);
    k_conv3x3<true><<<256, 256, 0, stream>>>(c1, rw2 + (size_t)i * 147456,
                                             rb2 + i * 128, st1, rg1 + i * 128,
                                             rbe1 + i * 128, c2);
    k_instats<<<64, 256, 0, stream>>>(c2, spart);
    k_statsreduce<<<NB, 256, 0, stream>>>(spart, st2);
    k_residual<<<1024, 256, 0, stream>>>(c2, st2, rg2 + i * 128, rbe2 + i * 128, wy);
  }

  k_final<<<1024, 256, 0, stream>>>(x, wy, mv, out);
}

// Round 3
// 339.477 us; speedup vs baseline: 2.7122x; 2.0154x over previous
//
#include <hip/hip_runtime.h>
#include <math.h>

constexpr int NB = 2;           // batch
constexpr int IMG = 64;         // H == W
constexpr int CH = 128;         // channels
constexpr int NT = IMG * IMG;   // 4096 tokens per batch
constexpr int ATT_KSPLIT = 8;
constexpr int KPS = NT / ATT_KSPLIT;  // 512 keys per split

typedef __bf16 bf16x8 __attribute__((ext_vector_type(8)));
typedef float f32x4 __attribute__((ext_vector_type(4)));

__device__ __forceinline__ unsigned f2bf(float x) {  // RNE float->bf16 bits
  unsigned u = __float_as_uint(x);
  return (u + 0x7fffu + ((u >> 16) & 1u)) >> 16;
}
__device__ __forceinline__ float bf2f(unsigned h) {
  return __uint_as_float(h << 16);
}

// ---------------------------------------------------------------- mask value
__global__ void k_init(const float* __restrict__ mask, float* __restrict__ mv) {
  const int i = blockIdx.x * 256 + threadIdx.x;
  if (i < NB * NT) {
    float mk = mask[i];
    float mm = mk > 0.f ? 0.f : mk;
    mv[i] = (1.f - mm) * (1.f - mk);
  }
}

// ---------------------------------------------------------------- weight prep
// Transpose each 128x128 [ci][co] f32 tile -> bf16 [co][136] (ci padded 128->136).
// Tiles: 0..53 = res conv taps (block i, conv1/conv2, tap), 54=wt 55=wp 56=wg 57=ww
__global__ __launch_bounds__(256) void k_prepw(
    const float* __restrict__ rw1, const float* __restrict__ rw2,
    const float* __restrict__ wt_, const float* __restrict__ wp_,
    const float* __restrict__ wg_, const float* __restrict__ ww_,
    unsigned short* __restrict__ wTpad) {
  __shared__ float Ws[128][132];
  const int t = threadIdx.x, bx = blockIdx.x;
  const float* src;
  if (bx < 54) {
    int i2 = bx / 9, tap = bx - i2 * 9;
    int blk = i2 >> 1;
    src = ((i2 & 1) ? rw2 : rw1) + ((size_t)blk * 9 + tap) * 16384;
  } else {
    src = bx == 54 ? wt_ : bx == 55 ? wp_ : bx == 56 ? wg_ : ww_;
  }
#pragma unroll
  for (int k = 0; k < 16; ++k) {
    int i4 = t + 256 * k;
    int row = i4 >> 5, c4 = (i4 & 31) << 2;
    *(float4*)&Ws[row][c4] = *(const float4*)(src + (size_t)row * 128 + c4);
  }
  __syncthreads();
  unsigned short* dst = wTpad + (size_t)bx * 17408;
#pragma unroll
  for (int k = 0; k < 9; ++k) {
    int it = t + 256 * k;
    if (it < 2176) {
      int g = it >> 7, co = it & 127, ci0 = g * 8;
      uint4 pk;
      if (ci0 < 128) {
        unsigned u0 = f2bf(Ws[ci0 + 0][co]) | (f2bf(Ws[ci0 + 1][co]) << 16);
        unsigned u1 = f2bf(Ws[ci0 + 2][co]) | (f2bf(Ws[ci0 + 3][co]) << 16);
        unsigned u2 = f2bf(Ws[ci0 + 4][co]) | (f2bf(Ws[ci0 + 5][co]) << 16);
        unsigned u3 = f2bf(Ws[ci0 + 6][co]) | (f2bf(Ws[ci0 + 7][co]) << 16);
        pk = make_uint4(u0, u1, u2, u3);
      } else {
        pk = make_uint4(0, 0, 0, 0);
      }
      *(uint4*)(dst + (size_t)co * 136 + ci0) = pk;
    }
  }
}

// ---------------------------------------------------------------- fused projections (MFMA)
// thb = x@wt+bt, phb = x@wp+bp, gxb = x@wg+bg   (all bf16 out)
__global__ __launch_bounds__(256) void k_proj3(
    const float* __restrict__ x, const unsigned short* __restrict__ wT3,
    const float* __restrict__ bt_, const float* __restrict__ bp_,
    const float* __restrict__ bg_, unsigned short* __restrict__ thb,
    unsigned short* __restrict__ phb, unsigned short* __restrict__ gxb) {
  __shared__ unsigned short Al[64 * 136];
  __shared__ unsigned short Wl[3 * 17408];
  const int t = threadIdx.x, r0 = blockIdx.x * 64;

  const uint4* ws = (const uint4*)wT3;
#pragma unroll
  for (int k = 0; k < 26; ++k) {
    int it = t + 256 * k;
    if (it < 6528) *(uint4*)&Wl[it * 8] = ws[it];
  }
#pragma unroll
  for (int k = 0; k < 4; ++k) {
    int it = t + 256 * k;
    int row = it >> 4, g = it & 15;
    const float* s = x + (size_t)(r0 + row) * 128 + g * 8;
    float4 v0 = *(const float4*)s, v1 = *(const float4*)(s + 4);
    uint4 pk;
    pk.x = f2bf(v0.x) | (f2bf(v0.y) << 16);
    pk.y = f2bf(v0.z) | (f2bf(v0.w) << 16);
    pk.z = f2bf(v1.x) | (f2bf(v1.y) << 16);
    pk.w = f2bf(v1.z) | (f2bf(v1.w) << 16);
    *(uint4*)&Al[row * 136 + g * 8] = pk;
  }
  __syncthreads();

  const int w = t >> 6, lane = t & 63, lg = lane >> 4, lc = lane & 15;
  const int mw = w & 1, nw = w >> 1;
#pragma unroll
  for (int mat = 0; mat < 3; ++mat) {
    f32x4 acc[2][4];
#pragma unroll
    for (int m = 0; m < 2; ++m)
#pragma unroll
      for (int n = 0; n < 4; ++n)
#pragma unroll
        for (int r = 0; r < 4; ++r) acc[m][n][r] = 0.f;
#pragma unroll
    for (int k = 0; k < 4; ++k) {
      bf16x8 a0 = *(const bf16x8*)&Al[(mw * 32 + lc) * 136 + k * 32 + lg * 8];
      bf16x8 a1 = *(const bf16x8*)&Al[(mw * 32 + 16 + lc) * 136 + k * 32 + lg * 8];
#pragma unroll
      for (int n = 0; n < 4; ++n) {
        bf16x8 bfr = *(const bf16x8*)&Wl[mat * 17408 + (nw * 64 + n * 16 + lc) * 136 + k * 32 + lg * 8];
        acc[0][n] = __builtin_amdgcn_mfma_f32_16x16x32_bf16(a0, bfr, acc[0][n], 0, 0, 0);
        acc[1][n] = __builtin_amdgcn_mfma_f32_16x16x32_bf16(a1, bfr, acc[1][n], 0, 0, 0);
      }
    }
    const float* bs = mat == 0 ? bt_ : mat == 1 ? bp_ : bg_;
    unsigned short* ob = mat == 0 ? thb : mat == 1 ? phb : gxb;
#pragma unroll
    for (int n = 0; n < 4; ++n) {
      int col = nw * 64 + n * 16 + lc;
      float bb = bs[col];
#pragma unroll
      for (int m = 0; m < 2; ++m)
#pragma unroll
        for (int r = 0; r < 4; ++r) {
          int row = r0 + mw * 32 + m * 16 + lg * 4 + r;
          ob[(size_t)row * 128 + col] = (unsigned short)f2bf(acc[m][n][r] + bb);
        }
    }
  }
}

// ---------------------------------------------------------------- W gemm: wy = y@ww+bw (f32 + bf16)
__global__ __launch_bounds__(256) void k_gemmW(
    const float* __restrict__ y, const unsigned short* __restrict__ wT,
    const float* __restrict__ bias, float* __restrict__ wy,
    unsigned short* __restrict__ wyb) {
  __shared__ unsigned short Al[64 * 136];
  __shared__ unsigned short Wl[17408];
  const int t = threadIdx.x, r0 = blockIdx.x * 64;

  const uint4* ws = (const uint4*)wT;
#pragma unroll
  for (int k = 0; k < 9; ++k) {
    int it = t + 256 * k;
    if (it < 2176) *(uint4*)&Wl[it * 8] = ws[it];
  }
#pragma unroll
  for (int k = 0; k < 4; ++k) {
    int it = t + 256 * k;
    int row = it >> 4, g = it & 15;
    const float* s = y + (size_t)(r0 + row) * 128 + g * 8;
    float4 v0 = *(const float4*)s, v1 = *(const float4*)(s + 4);
    uint4 pk;
    pk.x = f2bf(v0.x) | (f2bf(v0.y) << 16);
    pk.y = f2bf(v0.z) | (f2bf(v0.w) << 16);
    pk.z = f2bf(v1.x) | (f2bf(v1.y) << 16);
    pk.w = f2bf(v1.z) | (f2bf(v1.w) << 16);
    *(uint4*)&Al[row * 136 + g * 8] = pk;
  }
  __syncthreads();

  const int w = t >> 6, lane = t & 63, lg = lane >> 4, lc = lane & 15;
  const int mw = w & 1, nw = w >> 1;
  f32x4 acc[2][4];
#pragma unroll
  for (int m = 0; m < 2; ++m)
#pragma unroll
    for (int n = 0; n < 4; ++n)
#pragma unroll
      for (int r = 0; r < 4; ++r) acc[m][n][r] = 0.f;
#pragma unroll
  for (int k = 0; k < 4; ++k) {
    bf16x8 a0 = *(const bf16x8*)&Al[(mw * 32 + lc) * 136 + k * 32 + lg * 8];
    bf16x8 a1 = *(const bf16x8*)&Al[(mw * 32 + 16 + lc) * 136 + k * 32 + lg * 8];
#pragma unroll
    for (int n = 0; n < 4; ++n) {
      bf16x8 bfr = *(const bf16x8*)&Wl[(nw * 64 + n * 16 + lc) * 136 + k * 32 + lg * 8];
      acc[0][n] = __builtin_amdgcn_mfma_f32_16x16x32_bf16(a0, bfr, acc[0][n], 0, 0, 0);
      acc[1][n] = __builtin_amdgcn_mfma_f32_16x16x32_bf16(a1, bfr, acc[1][n], 0, 0, 0);
    }
  }
#pragma unroll
  for (int n = 0; n < 4; ++n) {
    int col = nw * 64 + n * 16 + lc;
    float bb = bias[col];
#pragma unroll
    for (int m = 0; m < 2; ++m)
#pragma unroll
      for (int r = 0; r < 4; ++r) {
        int row = r0 + mw * 32 + m * 16 + lg * 4 + r;
        float v = acc[m][n][r] + bb;
        wy[(size_t)row * 128 + col] = v;
        wyb[(size_t)row * 128 + col] = (unsigned short)f2bf(v);
      }
  }
}

// ---------------------------------------------------------------- transpose V (+mask scale)
__global__ __launch_bounds__(256) void k_transpose(
    const unsigned short* __restrict__ src, const float* __restrict__ mv,
    unsigned short* __restrict__ vt) {
  __shared__ __align__(16) unsigned short T[64][136];
  const int t = threadIdx.x;
  const int bx = blockIdx.x;
  const int b = bx >> 6;
  const int key0 = (bx & 63) * 64;
#pragma unroll
  for (int i = 0; i < 4; ++i) {
    int idx = t + 256 * i;
    int row = idx >> 4, c8 = (idx & 15) * 8;
    uint4 v = *(const uint4*)(src + ((size_t)(b * NT + key0 + row)) * CH + c8);
    float s = mv[b * NT + key0 + row];
    unsigned* vw = (unsigned*)&v;
#pragma unroll
    for (int q = 0; q < 4; ++q) {
      float lo = bf2f(vw[q] & 0xffffu) * s;
      float hi = bf2f(vw[q] >> 16) * s;
      vw[q] = f2bf(lo) | (f2bf(hi) << 16);
    }
    *(uint4*)&T[row][c8] = v;
  }
  __syncthreads();
  const int c = t >> 1, h = t & 1;
  unsigned buf[16];
#pragma unroll
  for (int j = 0; j < 16; ++j)
    buf[j] = (unsigned)T[h * 32 + 2 * j][c] | ((unsigned)T[h * 32 + 2 * j + 1][c] << 16);
  unsigned short* dst = vt + ((size_t)b * CH + c) * NT + key0 + h * 32;
  uint4* d4 = (uint4*)dst;
#pragma unroll
  for (int q = 0; q < 4; ++q)
    d4[q] = make_uint4(buf[4 * q], buf[4 * q + 1], buf[4 * q + 2], buf[4 * q + 3]);
}

// ---------------------------------------------------------------- flash attention (bf16 MFMA)
__global__ __launch_bounds__(256, 2) void k_attn(
    const unsigned short* __restrict__ theta, const unsigned short* __restrict__ phi,
    const unsigned short* __restrict__ vt, unsigned short* __restrict__ partO,
    float* __restrict__ partL) {
  __shared__ __align__(16) unsigned short Klds[64][136];
  __shared__ __align__(16) unsigned short Vtlds[128][72];
  __shared__ __align__(16) unsigned short Plds[4][32][72];

  const int t = threadIdx.x;
  const int bx = blockIdx.x;
  const int ks = bx & 7;
  const int qt = (bx >> 3) & 31;
  const int b = bx >> 8;
  const int w = t >> 6;
  const int lane = t & 63;
  const int lg = lane >> 4;
  const int lc = lane & 15;
  const int q0 = qt * 128 + w * 32;

  const unsigned short* thB = theta + (size_t)b * NT * CH;
  const unsigned short* phB = phi + (size_t)b * NT * CH;
  const unsigned short* vtB = vt + (size_t)b * CH * NT;

  bf16x8 qf[2][4];
#pragma unroll
  for (int q2 = 0; q2 < 2; ++q2)
#pragma unroll
    for (int k = 0; k < 4; ++k)
      qf[q2][k] = *(const bf16x8*)(thB + (size_t)(q0 + q2 * 16 + lc) * CH + k * 32 + lg * 8);

  f32x4 oacc[2][8];
#pragma unroll
  for (int q2 = 0; q2 < 2; ++q2)
#pragma unroll
    for (int c = 0; c < 8; ++c)
#pragma unroll
      for (int r = 0; r < 4; ++r) oacc[q2][c][r] = 0.f;
  float lsum[2][4] = {{0.f, 0.f, 0.f, 0.f}, {0.f, 0.f, 0.f, 0.f}};

  for (int kt = 0; kt < KPS; kt += 64) {
    const int key0 = ks * KPS + kt;
    __syncthreads();
#pragma unroll
    for (int i = 0; i < 4; ++i) {
      int idx = t + 256 * i;
      int row = idx >> 4, c8 = (idx & 15) * 8;
      *(uint4*)&Klds[row][c8] = *(const uint4*)(phB + (size_t)(key0 + row) * CH + c8);
      int rowv = idx >> 3, k8 = (idx & 7) * 8;
      *(uint4*)&Vtlds[rowv][k8] = *(const uint4*)(vtB + (size_t)rowv * NT + key0 + k8);
    }
    __syncthreads();

#pragma unroll
    for (int col = 0; col < 4; ++col) {
      bf16x8 kf[4];
#pragma unroll
      for (int k = 0; k < 4; ++k)
        kf[k] = *(const bf16x8*)&Klds[col * 16 + lc][k * 32 + lg * 8];
      f32x4 s0, s1;
#pragma unroll
      for (int r = 0; r < 4; ++r) { s0[r] = 0.f; s1[r] = 0.f; }
#pragma unroll
      for (int k = 0; k < 4; ++k) {
        s0 = __builtin_amdgcn_mfma_f32_16x16x32_bf16(qf[0][k], kf[k], s0, 0, 0, 0);
        s1 = __builtin_amdgcn_mfma_f32_16x16x32_bf16(qf[1][k], kf[k], s1, 0, 0, 0);
      }
#pragma unroll
      for (int r = 0; r < 4; ++r) {
        float p0 = __expf(s0[r]);
        lsum[0][r] += p0;
        Plds[w][lg * 4 + r][col * 16 + lc] = (unsigned short)f2bf(p0);
        float p1 = __expf(s1[r]);
        lsum[1][r] += p1;
        Plds[w][16 + lg * 4 + r][col * 16 + lc] = (unsigned short)f2bf(p1);
      }
    }

#pragma unroll
    for (int kp = 0; kp < 2; ++kp) {
      bf16x8 pa0 = *(const bf16x8*)&Plds[w][lc][kp * 32 + lg * 8];
      bf16x8 pa1 = *(const bf16x8*)&Plds[w][16 + lc][kp * 32 + lg * 8];
#pragma unroll
      for (int col = 0; col < 8; ++col) {
        bf16x8 vf = *(const bf16x8*)&Vtlds[col * 16 + lc][kp * 32 + lg * 8];
        oacc[0][col] = __builtin_amdgcn_mfma_f32_16x16x32_bf16(pa0, vf, oacc[0][col], 0, 0, 0);
        oacc[1][col] = __builtin_amdgcn_mfma_f32_16x16x32_bf16(pa1, vf, oacc[1][col], 0, 0, 0);
      }
    }
  }

#pragma unroll
  for (int off = 1; off < 16; off <<= 1)
#pragma unroll
    for (int q2 = 0; q2 < 2; ++q2)
#pragma unroll
      for (int r = 0; r < 4; ++r) lsum[q2][r] += __shfl_xor(lsum[q2][r], off);

  const size_t obase = ((size_t)ks * NB + b) * NT;
#pragma unroll
  for (int q2 = 0; q2 < 2; ++q2) {
#pragma unroll
    for (int col = 0; col < 8; ++col)
#pragma unroll
      for (int r = 0; r < 4; ++r) {
        int row = q0 + q2 * 16 + lg * 4 + r;
        partO[(obase + row) * CH + col * 16 + lc] = (unsigned short)f2bf(oacc[q2][col][r]);
      }
    if (lc == 0) {
#pragma unroll
      for (int r = 0; r < 4; ++r)
        partL[obase + q0 + q2 * 16 + lg * 4 + r] = lsum[q2][r];
    }
  }
}

// ---------------------------------------------------------------- combine ksplit partials
__global__ void k_attn_combine(const unsigned short* __restrict__ partO,
                               const float* __restrict__ partL,
                               float* __restrict__ y) {
  const int idx = blockIdx.x * 256 + threadIdx.x;
  const int c = (idx & 31) << 2;
  const size_t rowg = (size_t)(idx >> 5);
  float a0 = 0.f, a1 = 0.f, a2 = 0.f, a3 = 0.f, l = 0.f;
#pragma unroll
  for (int ksp = 0; ksp < ATT_KSPLIT; ++ksp) {
    const unsigned short* p = partO + ((size_t)ksp * NB * NT + rowg) * CH + c;
    uint2 u = *(const uint2*)p;
    a0 += bf2f(u.x & 0xffffu);
    a1 += bf2f(u.x >> 16);
    a2 += bf2f(u.y & 0xffffu);
    a3 += bf2f(u.y >> 16);
    l += partL[(size_t)ksp * NB * NT + rowg];
  }
  const float inv = 1.f / l;
  *(float4*)(y + rowg * CH + c) = make_float4(a0 * inv, a1 * inv, a2 * inv, a3 * inv);
}

// ---------------------------------------------------------------- 3x3 reflect conv (bf16 MFMA)
// in: act bf16 [b][64][64][128]; weights wT [9][128co][136ci] bf16.
// AFFINE: apply relu(a*val+b) (instance-norm of previous conv output) during staging.
// Writes bf16 output + per-(block,wavehalf) channel partial sums/sumsq for IN stats.
template <bool AFFINE>
__global__ __launch_bounds__(256) void k_conv(
    const unsigned short* __restrict__ act, const unsigned short* __restrict__ wT,
    const float* __restrict__ bias, const float* __restrict__ stats,
    const float* __restrict__ gamma, const float* __restrict__ beta,
    unsigned short* __restrict__ outc, float* __restrict__ part) {
  __shared__ unsigned short Alds[3][66 * 136];
  __shared__ unsigned short Wlds[2][17408];
  __shared__ float Aff[2][128];

  const int t = threadIdx.x, bx = blockIdx.x;
  const int b = bx >> 6, y = bx & 63;
  const int w = t >> 6, lane = t & 63, lg = lane >> 4, lc = lane & 15;
  const int mw = w & 1, nw = w >> 1;

  if constexpr (AFFINE) {
    if (t < 128) {
      const float* stb = stats + b * 256;
      float mean = stb[t * 2] * (1.f / 4096.f);
      float var = stb[t * 2 + 1] * (1.f / 4096.f) - mean * mean;
      float a = gamma[t] * rsqrtf(var + 1e-3f);
      Aff[0][t] = a;
      Aff[1][t] = beta[t] - mean * a;
    }
    __syncthreads();
  }

  uint4 wreg[9];
  auto loadW = [&](int tap) {
    const uint4* src = (const uint4*)(wT + (size_t)tap * 17408);
#pragma unroll
    for (int i = 0; i < 9; ++i) {
      int it = t + 256 * i;
      if (it < 2176) wreg[i] = src[it];
    }
  };
  auto writeW = [&](int buf) {
#pragma unroll
    for (int i = 0; i < 9; ++i) {
      int it = t + 256 * i;
      if (it < 2176) *(uint4*)&Wlds[buf][it * 8] = wreg[i];
    }
  };

  loadW(0);

  // stage A: 3 input rows (reflect), 66 columns, 128 ch bf16, padded stride 136
  const unsigned short* actB = act + (size_t)b * NT * CH;
#pragma unroll
  for (int i = 0; i < 13; ++i) {
    int it = t + 256 * i;
    if (it < 3168) {
      int r = it / 1056;
      int rem = it - r * 1056;
      int px = rem >> 4, g = rem & 15;
      int sy = y - 1 + r;
      sy = sy < 0 ? 1 : (sy > 63 ? 62 : sy);
      int sx = px - 1;
      sx = sx < 0 ? 1 : (sx > 63 ? 62 : sx);
      uint4 v = *(const uint4*)(actB + ((size_t)(sy * 64 + sx)) * CH + g * 8);
      if constexpr (AFFINE) {
        int c0 = g * 8;
        unsigned* vw = (unsigned*)&v;
#pragma unroll
        for (int q = 0; q < 4; ++q) {
          float x0 = bf2f(vw[q] & 0xffffu), x1 = bf2f(vw[q] >> 16);
          x0 = fmaxf(0.f, fmaf(Aff[0][c0 + 2 * q], x0, Aff[1][c0 + 2 * q]));
          x1 = fmaxf(0.f, fmaf(Aff[0][c0 + 2 * q + 1], x1, Aff[1][c0 + 2 * q + 1]));
          vw[q] = f2bf(x0) | (f2bf(x1) << 16);
        }
      }
      *(uint4*)&Alds[r][px * 136 + g * 8] = v;
    }
  }

  writeW(0);
  __syncthreads();
  loadW(1);

  f32x4 acc[2][4];
#pragma unroll
  for (int m = 0; m < 2; ++m)
#pragma unroll
    for (int n = 0; n < 4; ++n)
#pragma unroll
      for (int r = 0; r < 4; ++r) acc[m][n][r] = 0.f;

  const int xbase = mw * 32;
#pragma unroll
  for (int tap = 0; tap < 9; ++tap) {
    const int dy = tap / 3, dx = tap - dy * 3;
    const unsigned short* Wb = Wlds[tap & 1];
#pragma unroll
    for (int k = 0; k < 4; ++k) {
      bf16x8 a0 = *(const bf16x8*)&Alds[dy][(xbase + lc + dx) * 136 + k * 32 + lg * 8];
      bf16x8 a1 = *(const bf16x8*)&Alds[dy][(xbase + 16 + lc + dx) * 136 + k * 32 + lg * 8];
#pragma unroll
      for (int n = 0; n < 4; ++n) {
        bf16x8 bfr = *(const bf16x8*)&Wb[(nw * 64 + n * 16 + lc) * 136 + k * 32 + lg * 8];
        acc[0][n] = __builtin_amdgcn_mfma_f32_16x16x32_bf16(a0, bfr, acc[0][n], 0, 0, 0);
        acc[1][n] = __builtin_amdgcn_mfma_f32_16x16x32_bf16(a1, bfr, acc[1][n], 0, 0, 0);
      }
    }
    if (tap < 8) {
      writeW((tap + 1) & 1);
      if (tap < 7) loadW(tap + 2);
      __syncthreads();
    }
  }

  // epilogue: bias, bf16 store, per-channel partial stats
  float sum_[4] = {0.f, 0.f, 0.f, 0.f}, sq_[4] = {0.f, 0.f, 0.f, 0.f};
  unsigned short* outB = outc + ((size_t)(b * NT + y * 64)) * CH;
#pragma unroll
  for (int n = 0; n < 4; ++n) {
    int col = nw * 64 + n * 16 + lc;
    float bs = bias[col];
#pragma unroll
    for (int m = 0; m < 2; ++m)
#pragma unroll
      for (int r = 0; r < 4; ++r) {
        float v = acc[m][n][r] + bs;
        int x = xbase + m * 16 + lg * 4 + r;
        outB[(size_t)x * CH + col] = (unsigned short)f2bf(v);
        sum_[n] += v;
        sq_[n] = fmaf(v, v, sq_[n]);
      }
  }
#pragma unroll
  for (int off = 16; off < 64; off <<= 1)
#pragma unroll
    for (int n = 0; n < 4; ++n) {
      sum_[n] += __shfl_xor(sum_[n], off);
      sq_[n] += __shfl_xor(sq_[n], off);
    }
  if (lg == 0) {
    float* pr = part + (size_t)(bx * 2 + mw) * 256;
#pragma unroll
    for (int n = 0; n < 4; ++n) {
      int col = nw * 64 + n * 16 + lc;
      pr[col * 2] = sum_[n];
      pr[col * 2 + 1] = sq_[n];
    }
  }
}

// ---------------------------------------------------------------- stats reduce (128 partials/batch)
__global__ void k_statsred(const float* __restrict__ part, float* __restrict__ st) {
  const int b = blockIdx.x, t = threadIdx.x;
  float acc = 0.f;
  for (int k = 0; k < 128; ++k) acc += part[(size_t)(b * 128 + k) * 256 + t];
  st[b * 256 + t] = acc;
}

// ---------------------------------------------------------------- residual: wy += IN(c2); also bf16 copy
__global__ void k_residual(const unsigned short* __restrict__ c2v,
                           const float* __restrict__ st,
                           const float* __restrict__ gamma,
                           const float* __restrict__ beta, float* __restrict__ wy,
                           unsigned short* __restrict__ wyb) {
  const int idx = blockIdx.x * 256 + threadIdx.x;  // 131072 items (pixel, 8ch-group)
  const int g = idx & 15;
  const int pixel = idx >> 4;
  const int b = pixel >> 12;
  const int c0 = g * 8;
  const float* stb = st + b * 256;
  uint4 v = *(const uint4*)(c2v + (size_t)pixel * CH + c0);
  float* wp_ = wy + (size_t)pixel * CH + c0;
  float4 w0 = *(float4*)wp_, w1 = *(float4*)(wp_ + 4);
  float wv[8] = {w0.x, w0.y, w0.z, w0.w, w1.x, w1.y, w1.z, w1.w};
  const unsigned* vw = (const unsigned*)&v;
  float o[8];
#pragma unroll
  for (int q = 0; q < 8; ++q) {
    int ch = c0 + q;
    float mean = stb[ch * 2] * (1.f / 4096.f);
    float var = stb[ch * 2 + 1] * (1.f / 4096.f) - mean * mean;
    float a = gamma[ch] * rsqrtf(var + 1e-3f);
    float bb = beta[ch] - mean * a;
    float cv = bf2f((q & 1) ? (vw[q >> 1] >> 16) : (vw[q >> 1] & 0xffffu));
    o[q] = wv[q] + fmaf(a, cv, bb);
  }
  *(float4*)wp_ = make_float4(o[0], o[1], o[2], o[3]);
  *(float4*)(wp_ + 4) = make_float4(o[4], o[5], o[6], o[7]);
  uint4 pk;
  pk.x = f2bf(o[0]) | (f2bf(o[1]) << 16);
  pk.y = f2bf(o[2]) | (f2bf(o[3]) << 16);
  pk.z = f2bf(o[4]) | (f2bf(o[5]) << 16);
  pk.w = f2bf(o[6]) | (f2bf(o[7]) << 16);
  *(uint4*)(wyb + (size_t)pixel * CH + c0) = pk;
}

// ---------------------------------------------------------------- final blend
__global__ void k_final(const float* __restrict__ x, const float* __restrict__ wy,
                        const float* __restrict__ mv, float* __restrict__ out) {
  const int idx = blockIdx.x * 256 + threadIdx.x;
  const float m = mv[idx >> 5];
  const float4 xv = ((const float4*)x)[idx];
  const float4 wv = ((const float4*)wy)[idx];
  float4 o;
  o.x = m * xv.x + (1.f - m) * wv.x;
  o.y = m * xv.y + (1.f - m) * wv.y;
  o.z = m * xv.z + (1.f - m) * wv.z;
  o.w = m * xv.w + (1.f - m) * wv.w;
  ((float4*)out)[idx] = o;
}

// ================================================================ launch
extern "C" void kernel_launch(void* const* d_in, const int* in_sizes, int n_in,
                              void* d_out, int out_size, void* d_ws, size_t ws_size,
                              hipStream_t stream) {
  (void)in_sizes; (void)n_in; (void)out_size; (void)ws_size;
  const float* x    = (const float*)d_in[0];
  const float* mask = (const float*)d_in[1];
  const float* wg   = (const float*)d_in[2];
  const float* bg   = (const float*)d_in[3];
  const float* wt   = (const float*)d_in[4];
  const float* bt   = (const float*)d_in[5];
  const float* wp   = (const float*)d_in[6];
  const float* bp   = (const float*)d_in[7];
  const float* ww   = (const float*)d_in[8];
  const float* bw   = (const float*)d_in[9];
  const float* rw1  = (const float*)d_in[10];
  const float* rb1  = (const float*)d_in[11];
  const float* rg1  = (const float*)d_in[12];
  const float* rbe1 = (const float*)d_in[13];
  const float* rw2  = (const float*)d_in[14];
  const float* rb2  = (const float*)d_in[15];
  const float* rg2  = (const float*)d_in[16];
  const float* rbe2 = (const float*)d_in[17];
  float* out = (float*)d_out;

  char* W = (char*)d_ws;
  float*          mv    = (float*)(W + 0);                        // 32 KB
  unsigned short* wTpad = (unsigned short*)(W + 32768);           // 58*34816 B
  char* base = W + 32768 + 58 * 34816;                            // 2,052,096
  unsigned short* thb   = (unsigned short*)(base);                // 2 MB
  unsigned short* phb   = (unsigned short*)(base + 2097152);      // 2 MB
  unsigned short* gxb   = (unsigned short*)(base + 2 * 2097152);  // 2 MB
  unsigned short* vtb   = (unsigned short*)(base + 3 * 2097152);  // 2 MB
  float*          partL = (float*)(base + 4 * 2097152);           // 256 KB
  unsigned short* partO = (unsigned short*)(base + 4 * 2097152 + 262144);  // 16 MB
  // aliases over dead regions
  float*          y     = (float*)(base);                         // 4 MB over thb+phb
  float*          wy    = (float*)(base + 2 * 2097152);           // 4 MB over gxb+vtb
  unsigned short* c1    = partO;                                  // 2 MB
  unsigned short* c2    = (unsigned short*)((char*)partO + 2097152);      // 2 MB
  unsigned short* wyb   = (unsigned short*)((char*)partO + 2 * 2097152);  // 2 MB
  float*          part  = (float*)((char*)partO + 3 * 2097152);   // 256 KB
  float*          stats = (float*)((char*)partO + 3 * 2097152 + 262144);  // 12 KB

  k_init<<<32, 256, 0, stream>>>(mask, mv);
  k_prepw<<<58, 256, 0, stream>>>(rw1, rw2, wt, wp, wg, ww, wTpad);
  k_proj3<<<128, 256, 0, stream>>>(x, wTpad + (size_t)54 * 17408, bt, bp, bg,
                                   thb, phb, gxb);
  k_transpose<<<128, 256, 0, stream>>>(gxb, mv, vtb);
  k_attn<<<512, 256, 0, stream>>>(thb, phb, vtb, partO, partL);
  k_attn_combine<<<1024, 256, 0, stream>>>(partO, partL, y);
  k_gemmW<<<128, 256, 0, stream>>>(y, wTpad + (size_t)57 * 17408, bw, wy, wyb);

  for (int i = 0; i < 3; ++i) {
    float* st1 = stats + (2 * i) * 512;
    float* st2 = stats + (2 * i + 1) * 512;
    const unsigned short* wT1 = wTpad + (size_t)(2 * i) * 9 * 17408;
    const unsigned short* wT2 = wTpad + (size_t)(2 * i + 1) * 9 * 17408;
    k_conv<false><<<128, 256, 0, stream>>>(wyb, wT1, rb1 + i * 128, nullptr,
                                           nullptr, nullptr, c1, part);
    k_statsred<<<NB, 256, 0, stream>>>(part, st1);
    k_conv<true><<<128, 256, 0, stream>>>(c1, wT2, rb2 + i * 128, st1,
                                          rg1 + i * 128, rbe1 + i * 128, c2, part);
    k_statsred<<<NB, 256, 0, stream>>>(part, st2);
    k_residual<<<512, 256, 0, stream>>>(c2, st2, rg2 + i * 128, rbe2 + i * 128,
                                        wy, wyb);
  }

  k_final<<<1024, 256, 0, stream>>>(x, wy, mv, out);
}

// Round 4
// 168.724 us; speedup vs baseline: 5.4570x; 2.0120x over previous
//
#include <hip/hip_runtime.h>
#include <math.h>

constexpr int NB = 2;           // batch
constexpr int IMG = 64;         // H == W
constexpr int CH = 128;         // channels
constexpr int NT = IMG * IMG;   // 4096 tokens per batch
constexpr int ATT_KSPLIT = 8;
constexpr int KPS = NT / ATT_KSPLIT;  // 512 keys per split

typedef __bf16 bf16x8 __attribute__((ext_vector_type(8)));
typedef float f32x4 __attribute__((ext_vector_type(4)));

__device__ __forceinline__ unsigned f2bf(float x) {  // RNE float->bf16 bits
  unsigned u = __float_as_uint(x);
  return (u + 0x7fffu + ((u >> 16) & 1u)) >> 16;
}
__device__ __forceinline__ float bf2f(unsigned h) {
  return __uint_as_float(h << 16);
}

// ---------------------------------------------------------------- mask value
__global__ void k_init(const float* __restrict__ mask, float* __restrict__ mv) {
  const int i = blockIdx.x * 256 + threadIdx.x;
  if (i < NB * NT) {
    float mk = mask[i];
    float mm = mk > 0.f ? 0.f : mk;
    mv[i] = (1.f - mm) * (1.f - mk);
  }
}

// ---------------------------------------------------------------- weight prep
// Conv tiles (0..53): fragment-major bf16 layout [cotile(8)][k(4)][lane(64)][8ci]
//   per tap (16384 elems = 32 KB), so a wave's B-fragment load is lane*16B coalesced.
// GEMM tiles (54..57): padded-transpose bf16 [co][136ci] as before.
__global__ __launch_bounds__(256) void k_prepw(
    const float* __restrict__ rw1, const float* __restrict__ rw2,
    const float* __restrict__ wt_, const float* __restrict__ wp_,
    const float* __restrict__ wg_, const float* __restrict__ ww_,
    unsigned short* __restrict__ wTpad) {
  __shared__ float Ws[128][132];
  const int t = threadIdx.x, bx = blockIdx.x;
  const float* src;
  if (bx < 54) {
    int i2 = bx / 9, tap = bx - i2 * 9;
    int blk = i2 >> 1;
    src = ((i2 & 1) ? rw2 : rw1) + ((size_t)blk * 9 + tap) * 16384;
  } else {
    src = bx == 54 ? wt_ : bx == 55 ? wp_ : bx == 56 ? wg_ : ww_;
  }
#pragma unroll
  for (int k = 0; k < 16; ++k) {
    int i4 = t + 256 * k;
    int row = i4 >> 5, c4 = (i4 & 31) << 2;
    *(float4*)&Ws[row][c4] = *(const float4*)(src + (size_t)row * 128 + c4);
  }
  __syncthreads();
  if (bx < 54) {
    unsigned short* dst = wTpad + (size_t)bx * 16384;
#pragma unroll
    for (int i = 0; i < 8; ++i) {
      int idx = t + 256 * i;  // 0..2047 : cotile*256 + k*64 + lane
      int lane = idx & 63, k = (idx >> 6) & 3, cotile = idx >> 8;
      int lg = lane >> 4, lc = lane & 15;
      int co = cotile * 16 + lc, ci0 = k * 32 + lg * 8;
      unsigned u0 = f2bf(Ws[ci0 + 0][co]) | (f2bf(Ws[ci0 + 1][co]) << 16);
      unsigned u1 = f2bf(Ws[ci0 + 2][co]) | (f2bf(Ws[ci0 + 3][co]) << 16);
      unsigned u2 = f2bf(Ws[ci0 + 4][co]) | (f2bf(Ws[ci0 + 5][co]) << 16);
      unsigned u3 = f2bf(Ws[ci0 + 6][co]) | (f2bf(Ws[ci0 + 7][co]) << 16);
      *(uint4*)(dst + (size_t)idx * 8) = make_uint4(u0, u1, u2, u3);
    }
  } else {
    unsigned short* dst = wTpad + 884736 + (size_t)(bx - 54) * 17408;
#pragma unroll
    for (int k = 0; k < 9; ++k) {
      int it = t + 256 * k;
      if (it < 2176) {
        int g = it >> 7, co = it & 127, ci0 = g * 8;
        unsigned u0 = f2bf(Ws[ci0 + 0][co]) | (f2bf(Ws[ci0 + 1][co]) << 16);
        unsigned u1 = f2bf(Ws[ci0 + 2][co]) | (f2bf(Ws[ci0 + 3][co]) << 16);
        unsigned u2 = f2bf(Ws[ci0 + 4][co]) | (f2bf(Ws[ci0 + 5][co]) << 16);
        unsigned u3 = f2bf(Ws[ci0 + 6][co]) | (f2bf(Ws[ci0 + 7][co]) << 16);
        *(uint4*)(dst + (size_t)co * 136 + ci0) = make_uint4(u0, u1, u2, u3);
      }
    }
  }
}

// ---------------------------------------------------------------- fused projections (MFMA)
__global__ __launch_bounds__(256) void k_proj3(
    const float* __restrict__ x, const unsigned short* __restrict__ wT3,
    const float* __restrict__ bt_, const float* __restrict__ bp_,
    const float* __restrict__ bg_, unsigned short* __restrict__ thb,
    unsigned short* __restrict__ phb, unsigned short* __restrict__ gxb) {
  __shared__ unsigned short Al[64 * 136];
  __shared__ unsigned short Wl[3 * 17408];
  const int t = threadIdx.x, r0 = blockIdx.x * 64;

  const uint4* ws = (const uint4*)wT3;
#pragma unroll
  for (int k = 0; k < 26; ++k) {
    int it = t + 256 * k;
    if (it < 6528) *(uint4*)&Wl[it * 8] = ws[it];
  }
#pragma unroll
  for (int k = 0; k < 4; ++k) {
    int it = t + 256 * k;
    int row = it >> 4, g = it & 15;
    const float* s = x + (size_t)(r0 + row) * 128 + g * 8;
    float4 v0 = *(const float4*)s, v1 = *(const float4*)(s + 4);
    uint4 pk;
    pk.x = f2bf(v0.x) | (f2bf(v0.y) << 16);
    pk.y = f2bf(v0.z) | (f2bf(v0.w) << 16);
    pk.z = f2bf(v1.x) | (f2bf(v1.y) << 16);
    pk.w = f2bf(v1.z) | (f2bf(v1.w) << 16);
    *(uint4*)&Al[row * 136 + g * 8] = pk;
  }
  __syncthreads();

  const int w = t >> 6, lane = t & 63, lg = lane >> 4, lc = lane & 15;
  const int mw = w & 1, nw = w >> 1;
#pragma unroll
  for (int mat = 0; mat < 3; ++mat) {
    f32x4 acc[2][4];
#pragma unroll
    for (int m = 0; m < 2; ++m)
#pragma unroll
      for (int n = 0; n < 4; ++n)
#pragma unroll
        for (int r = 0; r < 4; ++r) acc[m][n][r] = 0.f;
#pragma unroll
    for (int k = 0; k < 4; ++k) {
      bf16x8 a0 = *(const bf16x8*)&Al[(mw * 32 + lc) * 136 + k * 32 + lg * 8];
      bf16x8 a1 = *(const bf16x8*)&Al[(mw * 32 + 16 + lc) * 136 + k * 32 + lg * 8];
#pragma unroll
      for (int n = 0; n < 4; ++n) {
        bf16x8 bfr = *(const bf16x8*)&Wl[mat * 17408 + (nw * 64 + n * 16 + lc) * 136 + k * 32 + lg * 8];
        acc[0][n] = __builtin_amdgcn_mfma_f32_16x16x32_bf16(a0, bfr, acc[0][n], 0, 0, 0);
        acc[1][n] = __builtin_amdgcn_mfma_f32_16x16x32_bf16(a1, bfr, acc[1][n], 0, 0, 0);
      }
    }
    const float* bs = mat == 0 ? bt_ : mat == 1 ? bp_ : bg_;
    unsigned short* ob = mat == 0 ? thb : mat == 1 ? phb : gxb;
#pragma unroll
    for (int n = 0; n < 4; ++n) {
      int col = nw * 64 + n * 16 + lc;
      float bb = bs[col];
#pragma unroll
      for (int m = 0; m < 2; ++m)
#pragma unroll
        for (int r = 0; r < 4; ++r) {
          int row = r0 + mw * 32 + m * 16 + lg * 4 + r;
          ob[(size_t)row * 128 + col] = (unsigned short)f2bf(acc[m][n][r] + bb);
        }
    }
  }
}

// ---------------------------------------------------------------- W gemm: wy = y@ww+bw (f32 + bf16)
__global__ __launch_bounds__(256) void k_gemmW(
    const float* __restrict__ y, const unsigned short* __restrict__ wT,
    const float* __restrict__ bias, float* __restrict__ wy,
    unsigned short* __restrict__ wyb) {
  __shared__ unsigned short Al[64 * 136];
  __shared__ unsigned short Wl[17408];
  const int t = threadIdx.x, r0 = blockIdx.x * 64;

  const uint4* ws = (const uint4*)wT;
#pragma unroll
  for (int k = 0; k < 9; ++k) {
    int it = t + 256 * k;
    if (it < 2176) *(uint4*)&Wl[it * 8] = ws[it];
  }
#pragma unroll
  for (int k = 0; k < 4; ++k) {
    int it = t + 256 * k;
    int row = it >> 4, g = it & 15;
    const float* s = y + (size_t)(r0 + row) * 128 + g * 8;
    float4 v0 = *(const float4*)s, v1 = *(const float4*)(s + 4);
    uint4 pk;
    pk.x = f2bf(v0.x) | (f2bf(v0.y) << 16);
    pk.y = f2bf(v0.z) | (f2bf(v0.w) << 16);
    pk.z = f2bf(v1.x) | (f2bf(v1.y) << 16);
    pk.w = f2bf(v1.z) | (f2bf(v1.w) << 16);
    *(uint4*)&Al[row * 136 + g * 8] = pk;
  }
  __syncthreads();

  const int w = t >> 6, lane = t & 63, lg = lane >> 4, lc = lane & 15;
  const int mw = w & 1, nw = w >> 1;
  f32x4 acc[2][4];
#pragma unroll
  for (int m = 0; m < 2; ++m)
#pragma unroll
    for (int n = 0; n < 4; ++n)
#pragma unroll
      for (int r = 0; r < 4; ++r) acc[m][n][r] = 0.f;
#pragma unroll
  for (int k = 0; k < 4; ++k) {
    bf16x8 a0 = *(const bf16x8*)&Al[(mw * 32 + lc) * 136 + k * 32 + lg * 8];
    bf16x8 a1 = *(const bf16x8*)&Al[(mw * 32 + 16 + lc) * 136 + k * 32 + lg * 8];
#pragma unroll
    for (int n = 0; n < 4; ++n) {
      bf16x8 bfr = *(const bf16x8*)&Wl[(nw * 64 + n * 16 + lc) * 136 + k * 32 + lg * 8];
      acc[0][n] = __builtin_amdgcn_mfma_f32_16x16x32_bf16(a0, bfr, acc[0][n], 0, 0, 0);
      acc[1][n] = __builtin_amdgcn_mfma_f32_16x16x32_bf16(a1, bfr, acc[1][n], 0, 0, 0);
    }
  }
#pragma unroll
  for (int n = 0; n < 4; ++n) {
    int col = nw * 64 + n * 16 + lc;
    float bb = bias[col];
#pragma unroll
    for (int m = 0; m < 2; ++m)
#pragma unroll
      for (int r = 0; r < 4; ++r) {
        int row = r0 + mw * 32 + m * 16 + lg * 4 + r;
        float v = acc[m][n][r] + bb;
        wy[(size_t)row * 128 + col] = v;
        wyb[(size_t)row * 128 + col] = (unsigned short)f2bf(v);
      }
  }
}

// ---------------------------------------------------------------- transpose V (+mask scale)
__global__ __launch_bounds__(256) void k_transpose(
    const unsigned short* __restrict__ src, const float* __restrict__ mv,
    unsigned short* __restrict__ vt) {
  __shared__ __align__(16) unsigned short T[64][136];
  const int t = threadIdx.x;
  const int bx = blockIdx.x;
  const int b = bx >> 6;
  const int key0 = (bx & 63) * 64;
#pragma unroll
  for (int i = 0; i < 4; ++i) {
    int idx = t + 256 * i;
    int row = idx >> 4, c8 = (idx & 15) * 8;
    uint4 v = *(const uint4*)(src + ((size_t)(b * NT + key0 + row)) * CH + c8);
    float s = mv[b * NT + key0 + row];
    unsigned* vw = (unsigned*)&v;
#pragma unroll
    for (int q = 0; q < 4; ++q) {
      float lo = bf2f(vw[q] & 0xffffu) * s;
      float hi = bf2f(vw[q] >> 16) * s;
      vw[q] = f2bf(lo) | (f2bf(hi) << 16);
    }
    *(uint4*)&T[row][c8] = v;
  }
  __syncthreads();
  const int c = t >> 1, h = t & 1;
  unsigned buf[16];
#pragma unroll
  for (int j = 0; j < 16; ++j)
    buf[j] = (unsigned)T[h * 32 + 2 * j][c] | ((unsigned)T[h * 32 + 2 * j + 1][c] << 16);
  unsigned short* dst = vt + ((size_t)b * CH + c) * NT + key0 + h * 32;
  uint4* d4 = (uint4*)dst;
#pragma unroll
  for (int q = 0; q < 4; ++q)
    d4[q] = make_uint4(buf[4 * q], buf[4 * q + 1], buf[4 * q + 2], buf[4 * q + 3]);
}

// ---------------------------------------------------------------- flash attention (bf16 MFMA)
__global__ __launch_bounds__(256, 2) void k_attn(
    const unsigned short* __restrict__ theta, const unsigned short* __restrict__ phi,
    const unsigned short* __restrict__ vt, unsigned short* __restrict__ partO,
    float* __restrict__ partL) {
  __shared__ __align__(16) unsigned short Klds[64][136];
  __shared__ __align__(16) unsigned short Vtlds[128][72];
  __shared__ __align__(16) unsigned short Plds[4][32][72];

  const int t = threadIdx.x;
  const int bx = blockIdx.x;
  const int ks = bx & 7;
  const int qt = (bx >> 3) & 31;
  const int b = bx >> 8;
  const int w = t >> 6;
  const int lane = t & 63;
  const int lg = lane >> 4;
  const int lc = lane & 15;
  const int q0 = qt * 128 + w * 32;

  const unsigned short* thB = theta + (size_t)b * NT * CH;
  const unsigned short* phB = phi + (size_t)b * NT * CH;
  const unsigned short* vtB = vt + (size_t)b * CH * NT;

  bf16x8 qf[2][4];
#pragma unroll
  for (int q2 = 0; q2 < 2; ++q2)
#pragma unroll
    for (int k = 0; k < 4; ++k)
      qf[q2][k] = *(const bf16x8*)(thB + (size_t)(q0 + q2 * 16 + lc) * CH + k * 32 + lg * 8);

  f32x4 oacc[2][8];
#pragma unroll
  for (int q2 = 0; q2 < 2; ++q2)
#pragma unroll
    for (int c = 0; c < 8; ++c)
#pragma unroll
      for (int r = 0; r < 4; ++r) oacc[q2][c][r] = 0.f;
  float lsum[2][4] = {{0.f, 0.f, 0.f, 0.f}, {0.f, 0.f, 0.f, 0.f}};

  for (int kt = 0; kt < KPS; kt += 64) {
    const int key0 = ks * KPS + kt;
    __syncthreads();
#pragma unroll
    for (int i = 0; i < 4; ++i) {
      int idx = t + 256 * i;
      int row = idx >> 4, c8 = (idx & 15) * 8;
      *(uint4*)&Klds[row][c8] = *(const uint4*)(phB + (size_t)(key0 + row) * CH + c8);
      int rowv = idx >> 3, k8 = (idx & 7) * 8;
      *(uint4*)&Vtlds[rowv][k8] = *(const uint4*)(vtB + (size_t)rowv * NT + key0 + k8);
    }
    __syncthreads();

#pragma unroll
    for (int col = 0; col < 4; ++col) {
      bf16x8 kf[4];
#pragma unroll
      for (int k = 0; k < 4; ++k)
        kf[k] = *(const bf16x8*)&Klds[col * 16 + lc][k * 32 + lg * 8];
      f32x4 s0, s1;
#pragma unroll
      for (int r = 0; r < 4; ++r) { s0[r] = 0.f; s1[r] = 0.f; }
#pragma unroll
      for (int k = 0; k < 4; ++k) {
        s0 = __builtin_amdgcn_mfma_f32_16x16x32_bf16(qf[0][k], kf[k], s0, 0, 0, 0);
        s1 = __builtin_amdgcn_mfma_f32_16x16x32_bf16(qf[1][k], kf[k], s1, 0, 0, 0);
      }
#pragma unroll
      for (int r = 0; r < 4; ++r) {
        float p0 = __expf(s0[r]);
        lsum[0][r] += p0;
        Plds[w][lg * 4 + r][col * 16 + lc] = (unsigned short)f2bf(p0);
        float p1 = __expf(s1[r]);
        lsum[1][r] += p1;
        Plds[w][16 + lg * 4 + r][col * 16 + lc] = (unsigned short)f2bf(p1);
      }
    }

#pragma unroll
    for (int kp = 0; kp < 2; ++kp) {
      bf16x8 pa0 = *(const bf16x8*)&Plds[w][lc][kp * 32 + lg * 8];
      bf16x8 pa1 = *(const bf16x8*)&Plds[w][16 + lc][kp * 32 + lg * 8];
#pragma unroll
      for (int col = 0; col < 8; ++col) {
        bf16x8 vf = *(const bf16x8*)&Vtlds[col * 16 + lc][kp * 32 + lg * 8];
        oacc[0][col] = __builtin_amdgcn_mfma_f32_16x16x32_bf16(pa0, vf, oacc[0][col], 0, 0, 0);
        oacc[1][col] = __builtin_amdgcn_mfma_f32_16x16x32_bf16(pa1, vf, oacc[1][col], 0, 0, 0);
      }
    }
  }

#pragma unroll
  for (int off = 1; off < 16; off <<= 1)
#pragma unroll
    for (int q2 = 0; q2 < 2; ++q2)
#pragma unroll
      for (int r = 0; r < 4; ++r) lsum[q2][r] += __shfl_xor(lsum[q2][r], off);

  const size_t obase = ((size_t)ks * NB + b) * NT;
#pragma unroll
  for (int q2 = 0; q2 < 2; ++q2) {
#pragma unroll
    for (int col = 0; col < 8; ++col)
#pragma unroll
      for (int r = 0; r < 4; ++r) {
        int row = q0 + q2 * 16 + lg * 4 + r;
        partO[(obase + row) * CH + col * 16 + lc] = (unsigned short)f2bf(oacc[q2][col][r]);
      }
    if (lc == 0) {
#pragma unroll
      for (int r = 0; r < 4; ++r)
        partL[obase + q0 + q2 * 16 + lg * 4 + r] = lsum[q2][r];
    }
  }
}

// ---------------------------------------------------------------- combine ksplit partials
__global__ void k_attn_combine(const unsigned short* __restrict__ partO,
                               const float* __restrict__ partL,
                               float* __restrict__ y) {
  const int idx = blockIdx.x * 256 + threadIdx.x;
  const int c = (idx & 31) << 2;
  const size_t rowg = (size_t)(idx >> 5);
  float a0 = 0.f, a1 = 0.f, a2 = 0.f, a3 = 0.f, l = 0.f;
#pragma unroll
  for (int ksp = 0; ksp < ATT_KSPLIT; ++ksp) {
    const unsigned short* p = partO + ((size_t)ksp * NB * NT + rowg) * CH + c;
    uint2 u = *(const uint2*)p;
    a0 += bf2f(u.x & 0xffffu);
    a1 += bf2f(u.x >> 16);
    a2 += bf2f(u.y & 0xffffu);
    a3 += bf2f(u.y >> 16);
    l += partL[(size_t)ksp * NB * NT + rowg];
  }
  const float inv = 1.f / l;
  *(float4*)(y + rowg * CH + c) = make_float4(a0 * inv, a1 * inv, a2 * inv, a3 * inv);
}

// ---------------------------------------------------------------- 3x3 reflect conv (bf16 MFMA, reg-weights)
// Block = 32 px (half row) x 64 co (half channels); 4 waves, wave = 32px x 16co.
// Weights read per-fragment from global (fragment-major layout, coalesced, L2-resident).
// A staged once in LDS (3 rows x 34 px, stride 136).
template <bool AFFINE>
__global__ __launch_bounds__(256) void k_conv(
    const unsigned short* __restrict__ act, const unsigned short* __restrict__ wf,
    const float* __restrict__ bias, const float* __restrict__ stats,
    const float* __restrict__ gamma, const float* __restrict__ beta,
    unsigned short* __restrict__ outc, float* __restrict__ part) {
  __shared__ unsigned short Alds[3][34 * 136];
  __shared__ float Aff[2][128];

  const int t = threadIdx.x, bx = blockIdx.x;
  const int ch = bx & 1, xh = (bx >> 1) & 1, y = (bx >> 2) & 63, b = bx >> 8;
  const int w = t >> 6, lane = t & 63, lg = lane >> 4, lc = lane & 15;
  const int x0 = xh * 32;
  const int coT = ch * 4 + w;  // global 16-col tile index 0..7

  if constexpr (AFFINE) {
    if (t < 128) {
      const float* stb = stats + b * 256;
      float mean = stb[t * 2] * (1.f / 4096.f);
      float var = stb[t * 2 + 1] * (1.f / 4096.f) - mean * mean;
      float a = gamma[t] * rsqrtf(var + 1e-3f);
      Aff[0][t] = a;
      Aff[1][t] = beta[t] - mean * a;
    }
    __syncthreads();
  }

  // stage A: 3 reflect-indexed input rows x 34 px x 128 ch
  const unsigned short* actB = act + (size_t)b * NT * CH;
#pragma unroll
  for (int i = 0; i < 7; ++i) {
    int it = t + 256 * i;
    if (it < 1632) {
      int r = it / 544, rem = it - r * 544;
      int px = rem >> 4, g = rem & 15;
      int sy = y - 1 + r;
      sy = sy < 0 ? 1 : (sy > 63 ? 62 : sy);
      int sx = x0 - 1 + px;
      sx = sx < 0 ? 1 : (sx > 63 ? 62 : sx);
      uint4 v = *(const uint4*)(actB + (size_t)(sy * 64 + sx) * CH + g * 8);
      if constexpr (AFFINE) {
        int c0 = g * 8;
        unsigned* vw = (unsigned*)&v;
#pragma unroll
        for (int q = 0; q < 4; ++q) {
          float v0 = bf2f(vw[q] & 0xffffu), v1 = bf2f(vw[q] >> 16);
          v0 = fmaxf(0.f, fmaf(Aff[0][c0 + 2 * q], v0, Aff[1][c0 + 2 * q]));
          v1 = fmaxf(0.f, fmaf(Aff[0][c0 + 2 * q + 1], v1, Aff[1][c0 + 2 * q + 1]));
          vw[q] = f2bf(v0) | (f2bf(v1) << 16);
        }
      }
      *(uint4*)&Alds[r][px * 136 + g * 8] = v;
    }
  }
  __syncthreads();

  f32x4 acc[2];
#pragma unroll
  for (int m = 0; m < 2; ++m)
#pragma unroll
    for (int r = 0; r < 4; ++r) acc[m][r] = 0.f;

  // fragment addr: wf + tap*16384 + coT*2048 + k*512 + lane*8
  const unsigned short* wbase = wf + (size_t)coT * 2048 + lane * 8;
  bf16x8 wc[4], wn[4];
#pragma unroll
  for (int k = 0; k < 4; ++k) wc[k] = *(const bf16x8*)(wbase + k * 512);
#pragma unroll
  for (int tap = 0; tap < 9; ++tap) {
    const int dy = tap / 3, dx = tap - dy * 3;
    if (tap < 8) {
#pragma unroll
      for (int k = 0; k < 4; ++k)
        wn[k] = *(const bf16x8*)(wbase + (size_t)(tap + 1) * 16384 + k * 512);
    }
#pragma unroll
    for (int k = 0; k < 4; ++k) {
      bf16x8 a0 = *(const bf16x8*)&Alds[dy][(dx + lc) * 136 + k * 32 + lg * 8];
      bf16x8 a1 = *(const bf16x8*)&Alds[dy][(dx + 16 + lc) * 136 + k * 32 + lg * 8];
      acc[0] = __builtin_amdgcn_mfma_f32_16x16x32_bf16(a0, wc[k], acc[0], 0, 0, 0);
      acc[1] = __builtin_amdgcn_mfma_f32_16x16x32_bf16(a1, wc[k], acc[1], 0, 0, 0);
    }
#pragma unroll
    for (int k = 0; k < 4; ++k) wc[k] = wn[k];
  }

  // epilogue: bias, bf16 store, per-channel stats partials (transposed layout)
  const int col = coT * 16 + lc;
  const float bs = bias[col];
  float sum = 0.f, sq = 0.f;
  unsigned short* outB = outc + (size_t)(b * NT + y * 64 + x0) * CH;
#pragma unroll
  for (int m = 0; m < 2; ++m)
#pragma unroll
    for (int r = 0; r < 4; ++r) {
      float v = acc[m][r] + bs;
      int px = m * 16 + lg * 4 + r;
      outB[(size_t)px * CH + col] = (unsigned short)f2bf(v);
      sum += v;
      sq = fmaf(v, v, sq);
    }
  sum += __shfl_xor(sum, 16);
  sum += __shfl_xor(sum, 32);
  sq += __shfl_xor(sq, 16);
  sq += __shfl_xor(sq, 32);
  if (lg == 0) {
    const int pg = y * 2 + xh;  // 0..127
    part[((size_t)(b * 128 + col) * 2 + 0) * 128 + pg] = sum;
    part[((size_t)(b * 128 + col) * 2 + 1) * 128 + pg] = sq;
  }
}

// ---------------------------------------------------------------- stats reduce
// part[(b*256 + ch*2 + s)*128 + pg] -> st[b*256 + ch*2 + s]; contiguous 512B per thread
__global__ void k_statsred(const float* __restrict__ part, float* __restrict__ st) {
  const int b = blockIdx.x, t = threadIdx.x;
  const float* p = part + ((size_t)b * 256 + t) * 128;
  float acc = 0.f;
#pragma unroll 8
  for (int k = 0; k < 128; ++k) acc += p[k];
  st[b * 256 + t] = acc;
}

// ---------------------------------------------------------------- residual: wy += IN(c2); also bf16 copy
__global__ void k_residual(const unsigned short* __restrict__ c2v,
                           const float* __restrict__ st,
                           const float* __restrict__ gamma,
                           const float* __restrict__ beta, float* __restrict__ wy,
                           unsigned short* __restrict__ wyb) {
  const int idx = blockIdx.x * 256 + threadIdx.x;  // 131072 items (pixel, 8ch-group)
  const int g = idx & 15;
  const int pixel = idx >> 4;
  const int b = pixel >> 12;
  const int c0 = g * 8;
  const float* stb = st + b * 256;
  uint4 v = *(const uint4*)(c2v + (size_t)pixel * CH + c0);
  float* wp_ = wy + (size_t)pixel * CH + c0;
  float4 w0 = *(float4*)wp_, w1 = *(float4*)(wp_ + 4);
  float wv[8] = {w0.x, w0.y, w0.z, w0.w, w1.x, w1.y, w1.z, w1.w};
  const unsigned* vw = (const unsigned*)&v;
  float o[8];
#pragma unroll
  for (int q = 0; q < 8; ++q) {
    int ch = c0 + q;
    float mean = stb[ch * 2] * (1.f / 4096.f);
    float var = stb[ch * 2 + 1] * (1.f / 4096.f) - mean * mean;
    float a = gamma[ch] * rsqrtf(var + 1e-3f);
    float bb = beta[ch] - mean * a;
    float cv = bf2f((q & 1) ? (vw[q >> 1] >> 16) : (vw[q >> 1] & 0xffffu));
    o[q] = wv[q] + fmaf(a, cv, bb);
  }
  *(float4*)wp_ = make_float4(o[0], o[1], o[2], o[3]);
  *(float4*)(wp_ + 4) = make_float4(o[4], o[5], o[6], o[7]);
  uint4 pk;
  pk.x = f2bf(o[0]) | (f2bf(o[1]) << 16);
  pk.y = f2bf(o[2]) | (f2bf(o[3]) << 16);
  pk.z = f2bf(o[4]) | (f2bf(o[5]) << 16);
  pk.w = f2bf(o[6]) | (f2bf(o[7]) << 16);
  *(uint4*)(wyb + (size_t)pixel * CH + c0) = pk;
}

// ---------------------------------------------------------------- final blend
__global__ void k_final(const float* __restrict__ x, const float* __restrict__ wy,
                        const float* __restrict__ mv, float* __restrict__ out) {
  const int idx = blockIdx.x * 256 + threadIdx.x;
  const float m = mv[idx >> 5];
  const float4 xv = ((const float4*)x)[idx];
  const float4 wv = ((const float4*)wy)[idx];
  float4 o;
  o.x = m * xv.x + (1.f - m) * wv.x;
  o.y = m * xv.y + (1.f - m) * wv.y;
  o.z = m * xv.z + (1.f - m) * wv.z;
  o.w = m * xv.w + (1.f - m) * wv.w;
  ((float4*)out)[idx] = o;
}

// ================================================================ launch
extern "C" void kernel_launch(void* const* d_in, const int* in_sizes, int n_in,
                              void* d_out, int out_size, void* d_ws, size_t ws_size,
                              hipStream_t stream) {
  (void)in_sizes; (void)n_in; (void)out_size; (void)ws_size;
  const float* x    = (const float*)d_in[0];
  const float* mask = (const float*)d_in[1];
  const float* wg   = (const float*)d_in[2];
  const float* bg   = (const float*)d_in[3];
  const float* wt   = (const float*)d_in[4];
  const float* bt   = (const float*)d_in[5];
  const float* wp   = (const float*)d_in[6];
  const float* bp   = (const float*)d_in[7];
  const float* ww   = (const float*)d_in[8];
  const float* bw   = (const float*)d_in[9];
  const float* rw1  = (const float*)d_in[10];
  const float* rb1  = (const float*)d_in[11];
  const float* rg1  = (const float*)d_in[12];
  const float* rbe1 = (const float*)d_in[13];
  const float* rw2  = (const float*)d_in[14];
  const float* rb2  = (const float*)d_in[15];
  const float* rg2  = (const float*)d_in[16];
  const float* rbe2 = (const float*)d_in[17];
  float* out = (float*)d_out;

  char* W = (char*)d_ws;
  float*          mv    = (float*)(W + 0);                        // 32 KB
  unsigned short* wfrag = (unsigned short*)(W + 32768);           // 54*32 KB conv frags
  unsigned short* wpad  = wfrag + 884736;                         // 4*34816 B gemm tiles
  char* base = W + 32768 + 1908736;                               // = W + 1941504
  unsigned short* thb   = (unsigned short*)(base);                // 2 MB
  unsigned short* phb   = (unsigned short*)(base + 2097152);      // 2 MB
  unsigned short* gxb   = (unsigned short*)(base + 2 * 2097152);  // 2 MB
  unsigned short* vtb   = (unsigned short*)(base + 3 * 2097152);  // 2 MB
  float*          partL = (float*)(base + 4 * 2097152);           // 256 KB
  unsigned short* partO = (unsigned short*)(base + 4 * 2097152 + 262144);  // 16 MB
  // aliases over dead regions
  float*          y     = (float*)(base);                         // 4 MB over thb+phb
  float*          wy    = (float*)(base + 2 * 2097152);           // 4 MB over gxb+vtb
  unsigned short* c1    = partO;                                  // 2 MB
  unsigned short* c2    = (unsigned short*)((char*)partO + 2097152);      // 2 MB
  unsigned short* wyb   = (unsigned short*)((char*)partO + 2 * 2097152);  // 2 MB
  float*          part  = (float*)((char*)partO + 3 * 2097152);   // 256 KB
  float*          stats = (float*)((char*)partO + 3 * 2097152 + 262144);  // 12 KB

  k_init<<<32, 256, 0, stream>>>(mask, mv);
  k_prepw<<<58, 256, 0, stream>>>(rw1, rw2, wt, wp, wg, ww, wfrag);
  k_proj3<<<128, 256, 0, stream>>>(x, wpad, bt, bp, bg, thb, phb, gxb);
  k_transpose<<<128, 256, 0, stream>>>(gxb, mv, vtb);
  k_attn<<<512, 256, 0, stream>>>(thb, phb, vtb, partO, partL);
  k_attn_combine<<<1024, 256, 0, stream>>>(partO, partL, y);
  k_gemmW<<<128, 256, 0, stream>>>(y, wpad + (size_t)3 * 17408, bw, wy, wyb);

  for (int i = 0; i < 3; ++i) {
    float* st1 = stats + (2 * i) * 512;
    float* st2 = stats + (2 * i + 1) * 512;
    const unsigned short* wf1 = wfrag + (size_t)(2 * i) * 9 * 16384;
    const unsigned short* wf2 = wfrag + (size_t)(2 * i + 1) * 9 * 16384;
    k_conv<false><<<512, 256, 0, stream>>>(wyb, wf1, rb1 + i * 128, nullptr,
                                           nullptr, nullptr, c1, part);
    k_statsred<<<NB, 256, 0, stream>>>(part, st1);
    k_conv<true><<<512, 256, 0, stream>>>(c1, wf2, rb2 + i * 128, st1,
                                          rg1 + i * 128, rbe1 + i * 128, c2, part);
    k_statsred<<<NB, 256, 0, stream>>>(part, st2);
    k_residual<<<512, 256, 0, stream>>>(c2, st2, rg2 + i * 128, rbe2 + i * 128,
                                        wy, wyb);
  }

  k_final<<<1024, 256, 0, stream>>>(x, wy, mv, out);
}

// Round 5
// 166.517 us; speedup vs baseline: 5.5293x; 1.0133x over previous
//
#include <hip/hip_runtime.h>
#include <math.h>

constexpr int NB = 2;           // batch
constexpr int IMG = 64;         // H == W
constexpr int CH = 128;         // channels
constexpr int NT = IMG * IMG;   // 4096 tokens per batch
constexpr int ATT_KSPLIT = 8;
constexpr int KPS = NT / ATT_KSPLIT;  // 512 keys per split

typedef __bf16 bf16x8 __attribute__((ext_vector_type(8)));
typedef float f32x4 __attribute__((ext_vector_type(4)));

__device__ __forceinline__ unsigned f2bf(float x) {  // RNE float->bf16 bits
  unsigned u = __float_as_uint(x);
  return (u + 0x7fffu + ((u >> 16) & 1u)) >> 16;
}
__device__ __forceinline__ float bf2f(unsigned h) {
  return __uint_as_float(h << 16);
}
__device__ __forceinline__ float maskval(float mk) {
  float mm = mk > 0.f ? 0.f : mk;
  return (1.f - mm) * (1.f - mk);
}

// ---------------------------------------------------------------- weight prep
// ALL 58 tiles in fragment-major bf16 layout [cotile(8)][k(4)][lane(64)][8ci]
// (16384 elems = 32 KB per tile): a wave's B-fragment is one lane*16B coalesced load.
// Tiles 0..53 = res conv taps (block, conv1/2, tap); 54=wt 55=wp 56=wg 57=ww.
__global__ __launch_bounds__(256) void k_prepw(
    const float* __restrict__ rw1, const float* __restrict__ rw2,
    const float* __restrict__ wt_, const float* __restrict__ wp_,
    const float* __restrict__ wg_, const float* __restrict__ ww_,
    unsigned short* __restrict__ wfrag) {
  __shared__ float Ws[128][132];
  const int t = threadIdx.x, bx = blockIdx.x;
  const float* src;
  if (bx < 54) {
    int i2 = bx / 9, tap = bx - i2 * 9;
    int blk = i2 >> 1;
    src = ((i2 & 1) ? rw2 : rw1) + ((size_t)blk * 9 + tap) * 16384;
  } else {
    src = bx == 54 ? wt_ : bx == 55 ? wp_ : bx == 56 ? wg_ : ww_;
  }
#pragma unroll
  for (int k = 0; k < 16; ++k) {
    int i4 = t + 256 * k;
    int row = i4 >> 5, c4 = (i4 & 31) << 2;
    *(float4*)&Ws[row][c4] = *(const float4*)(src + (size_t)row * 128 + c4);
  }
  __syncthreads();
  unsigned short* dst = wfrag + (size_t)bx * 16384;
#pragma unroll
  for (int i = 0; i < 8; ++i) {
    int idx = t + 256 * i;  // cotile*256 + k*64 + lane
    int lane = idx & 63, k = (idx >> 6) & 3, cotile = idx >> 8;
    int lg = lane >> 4, lc = lane & 15;
    int co = cotile * 16 + lc, ci0 = k * 32 + lg * 8;
    unsigned u0 = f2bf(Ws[ci0 + 0][co]) | (f2bf(Ws[ci0 + 1][co]) << 16);
    unsigned u1 = f2bf(Ws[ci0 + 2][co]) | (f2bf(Ws[ci0 + 3][co]) << 16);
    unsigned u2 = f2bf(Ws[ci0 + 4][co]) | (f2bf(Ws[ci0 + 5][co]) << 16);
    unsigned u3 = f2bf(Ws[ci0 + 6][co]) | (f2bf(Ws[ci0 + 7][co]) << 16);
    *(uint4*)(dst + (size_t)idx * 8) = make_uint4(u0, u1, u2, u3);
  }
}

// ---------------------------------------------------------------- fused projections
// thb = x@wt+bt, phb = x@wp+bp (bf16); V = (x@wg+bg)*mv written TRANSPOSED to vtb.
// Weights read fragment-major from global (L2-resident) -> registers; no weight LDS.
__global__ __launch_bounds__(256) void k_proj3(
    const float* __restrict__ x, const float* __restrict__ mask,
    const unsigned short* __restrict__ wf, const float* __restrict__ bt_,
    const float* __restrict__ bp_, const float* __restrict__ bg_,
    unsigned short* __restrict__ thb, unsigned short* __restrict__ phb,
    unsigned short* __restrict__ vtb) {
  __shared__ __align__(16) unsigned short Al[64 * 136];
  __shared__ __align__(16) unsigned short Tl[64 * 136];
  const int t = threadIdx.x, r0 = blockIdx.x * 64, b = r0 >> 12;

#pragma unroll
  for (int k = 0; k < 4; ++k) {
    int it = t + 256 * k;
    int row = it >> 4, g = it & 15;
    const float* s = x + (size_t)(r0 + row) * 128 + g * 8;
    float4 v0 = *(const float4*)s, v1 = *(const float4*)(s + 4);
    uint4 pk;
    pk.x = f2bf(v0.x) | (f2bf(v0.y) << 16);
    pk.y = f2bf(v0.z) | (f2bf(v0.w) << 16);
    pk.z = f2bf(v1.x) | (f2bf(v1.y) << 16);
    pk.w = f2bf(v1.z) | (f2bf(v1.w) << 16);
    *(uint4*)&Al[row * 136 + g * 8] = pk;
  }
  __syncthreads();

  const int w = t >> 6, lane = t & 63, lg = lane >> 4, lc = lane & 15;
  const int mw = w & 1, nw = w >> 1;
#pragma unroll
  for (int mat = 0; mat < 3; ++mat) {
    f32x4 acc[2][4];
#pragma unroll
    for (int m = 0; m < 2; ++m)
#pragma unroll
      for (int n = 0; n < 4; ++n)
#pragma unroll
        for (int r = 0; r < 4; ++r) acc[m][n][r] = 0.f;
    const unsigned short* wb =
        wf + (size_t)(54 + mat) * 16384 + (size_t)(nw * 4) * 2048 + lane * 8;
#pragma unroll
    for (int k = 0; k < 4; ++k) {
      bf16x8 a0 = *(const bf16x8*)&Al[(mw * 32 + lc) * 136 + k * 32 + lg * 8];
      bf16x8 a1 = *(const bf16x8*)&Al[(mw * 32 + 16 + lc) * 136 + k * 32 + lg * 8];
#pragma unroll
      for (int n = 0; n < 4; ++n) {
        bf16x8 bfr = *(const bf16x8*)(wb + n * 2048 + k * 512);
        acc[0][n] = __builtin_amdgcn_mfma_f32_16x16x32_bf16(a0, bfr, acc[0][n], 0, 0, 0);
        acc[1][n] = __builtin_amdgcn_mfma_f32_16x16x32_bf16(a1, bfr, acc[1][n], 0, 0, 0);
      }
    }
    const float* bs = mat == 0 ? bt_ : mat == 1 ? bp_ : bg_;
    float bbv[4];
#pragma unroll
    for (int n = 0; n < 4; ++n) bbv[n] = bs[nw * 64 + n * 16 + lc];

    if (mat < 2) {
      unsigned short* ob = mat == 0 ? thb : phb;
#pragma unroll
      for (int n = 0; n < 4; ++n) {
        int col = nw * 64 + n * 16 + lc;
#pragma unroll
        for (int m = 0; m < 2; ++m)
#pragma unroll
          for (int r = 0; r < 4; ++r) {
            int row = r0 + mw * 32 + m * 16 + lg * 4 + r;
            ob[(size_t)row * 128 + col] = (unsigned short)f2bf(acc[m][n][r] + bbv[n]);
          }
      }
    } else {
      // V: apply mask scale per key row, stash bf16 into Tl, then transpose-write
#pragma unroll
      for (int m = 0; m < 2; ++m)
#pragma unroll
        for (int r = 0; r < 4; ++r) {
          int rl = mw * 32 + m * 16 + lg * 4 + r;
          float mvv = maskval(mask[r0 + rl]);
#pragma unroll
          for (int n = 0; n < 4; ++n) {
            int col = nw * 64 + n * 16 + lc;
            Tl[rl * 136 + col] = (unsigned short)f2bf((acc[m][n][r] + bbv[n]) * mvv);
          }
        }
      __syncthreads();
      const int c = t >> 1, h = t & 1;
      unsigned buf[16];
#pragma unroll
      for (int j = 0; j < 16; ++j)
        buf[j] = (unsigned)Tl[(h * 32 + 2 * j) * 136 + c] |
                 ((unsigned)Tl[(h * 32 + 2 * j + 1) * 136 + c] << 16);
      const int key0 = r0 & (NT - 1);
      unsigned short* dst = vtb + ((size_t)b * CH + c) * NT + key0 + h * 32;
      uint4* d4 = (uint4*)dst;
#pragma unroll
      for (int q = 0; q < 4; ++q)
        d4[q] = make_uint4(buf[4 * q], buf[4 * q + 1], buf[4 * q + 2], buf[4 * q + 3]);
    }
  }
}

// ---------------------------------------------------------------- flash attention (bf16 MFMA)
__global__ __launch_bounds__(256, 2) void k_attn(
    const unsigned short* __restrict__ theta, const unsigned short* __restrict__ phi,
    const unsigned short* __restrict__ vt, unsigned short* __restrict__ partO,
    float* __restrict__ partL) {
  __shared__ __align__(16) unsigned short Klds[64][136];
  __shared__ __align__(16) unsigned short Vtlds[128][72];
  __shared__ __align__(16) unsigned short Plds[4][32][72];

  const int t = threadIdx.x;
  const int bx = blockIdx.x;
  const int ks = bx & 7;
  const int qt = (bx >> 3) & 31;
  const int b = bx >> 8;
  const int w = t >> 6;
  const int lane = t & 63;
  const int lg = lane >> 4;
  const int lc = lane & 15;
  const int q0 = qt * 128 + w * 32;

  const unsigned short* thB = theta + (size_t)b * NT * CH;
  const unsigned short* phB = phi + (size_t)b * NT * CH;
  const unsigned short* vtB = vt + (size_t)b * CH * NT;

  bf16x8 qf[2][4];
#pragma unroll
  for (int q2 = 0; q2 < 2; ++q2)
#pragma unroll
    for (int k = 0; k < 4; ++k)
      qf[q2][k] = *(const bf16x8*)(thB + (size_t)(q0 + q2 * 16 + lc) * CH + k * 32 + lg * 8);

  f32x4 oacc[2][8];
#pragma unroll
  for (int q2 = 0; q2 < 2; ++q2)
#pragma unroll
    for (int c = 0; c < 8; ++c)
#pragma unroll
      for (int r = 0; r < 4; ++r) oacc[q2][c][r] = 0.f;
  float lsum[2][4] = {{0.f, 0.f, 0.f, 0.f}, {0.f, 0.f, 0.f, 0.f}};

  for (int kt = 0; kt < KPS; kt += 64) {
    const int key0 = ks * KPS + kt;
    __syncthreads();
#pragma unroll
    for (int i = 0; i < 4; ++i) {
      int idx = t + 256 * i;
      int row = idx >> 4, c8 = (idx & 15) * 8;
      *(uint4*)&Klds[row][c8] = *(const uint4*)(phB + (size_t)(key0 + row) * CH + c8);
      int rowv = idx >> 3, k8 = (idx & 7) * 8;
      *(uint4*)&Vtlds[rowv][k8] = *(const uint4*)(vtB + (size_t)rowv * NT + key0 + k8);
    }
    __syncthreads();

#pragma unroll
    for (int col = 0; col < 4; ++col) {
      bf16x8 kf[4];
#pragma unroll
      for (int k = 0; k < 4; ++k)
        kf[k] = *(const bf16x8*)&Klds[col * 16 + lc][k * 32 + lg * 8];
      f32x4 s0, s1;
#pragma unroll
      for (int r = 0; r < 4; ++r) { s0[r] = 0.f; s1[r] = 0.f; }
#pragma unroll
      for (int k = 0; k < 4; ++k) {
        s0 = __builtin_amdgcn_mfma_f32_16x16x32_bf16(qf[0][k], kf[k], s0, 0, 0, 0);
        s1 = __builtin_amdgcn_mfma_f32_16x16x32_bf16(qf[1][k], kf[k], s1, 0, 0, 0);
      }
#pragma unroll
      for (int r = 0; r < 4; ++r) {
        float p0 = __expf(s0[r]);
        lsum[0][r] += p0;
        Plds[w][lg * 4 + r][col * 16 + lc] = (unsigned short)f2bf(p0);
        float p1 = __expf(s1[r]);
        lsum[1][r] += p1;
        Plds[w][16 + lg * 4 + r][col * 16 + lc] = (unsigned short)f2bf(p1);
      }
    }

#pragma unroll
    for (int kp = 0; kp < 2; ++kp) {
      bf16x8 pa0 = *(const bf16x8*)&Plds[w][lc][kp * 32 + lg * 8];
      bf16x8 pa1 = *(const bf16x8*)&Plds[w][16 + lc][kp * 32 + lg * 8];
#pragma unroll
      for (int col = 0; col < 8; ++col) {
        bf16x8 vf = *(const bf16x8*)&Vtlds[col * 16 + lc][kp * 32 + lg * 8];
        oacc[0][col] = __builtin_amdgcn_mfma_f32_16x16x32_bf16(pa0, vf, oacc[0][col], 0, 0, 0);
        oacc[1][col] = __builtin_amdgcn_mfma_f32_16x16x32_bf16(pa1, vf, oacc[1][col], 0, 0, 0);
      }
    }
  }

#pragma unroll
  for (int off = 1; off < 16; off <<= 1)
#pragma unroll
    for (int q2 = 0; q2 < 2; ++q2)
#pragma unroll
      for (int r = 0; r < 4; ++r) lsum[q2][r] += __shfl_xor(lsum[q2][r], off);

  const size_t obase = ((size_t)ks * NB + b) * NT;
#pragma unroll
  for (int q2 = 0; q2 < 2; ++q2) {
#pragma unroll
    for (int col = 0; col < 8; ++col)
#pragma unroll
      for (int r = 0; r < 4; ++r) {
        int row = q0 + q2 * 16 + lg * 4 + r;
        partO[(obase + row) * CH + col * 16 + lc] = (unsigned short)f2bf(oacc[q2][col][r]);
      }
    if (lc == 0) {
#pragma unroll
      for (int r = 0; r < 4; ++r)
        partL[obase + q0 + q2 * 16 + lg * 4 + r] = lsum[q2][r];
    }
  }
}

// ---------------------------------------------------------------- W gemm, fused combine
// stages y = (sum_ks partO)/(sum_ks partL) as bf16, then y@ww+bw -> wy f32 + wyb bf16
__global__ __launch_bounds__(256) void k_gemmW(
    const unsigned short* __restrict__ partO, const float* __restrict__ partL,
    const unsigned short* __restrict__ wf, const float* __restrict__ bias,
    float* __restrict__ wy, unsigned short* __restrict__ wyb) {
  __shared__ __align__(16) unsigned short Al[64 * 136];
  __shared__ float linv[64];
  const int t = threadIdx.x, r0 = blockIdx.x * 64;

  if (t < 64) {
    float l = 0.f;
#pragma unroll
    for (int ks = 0; ks < ATT_KSPLIT; ++ks) l += partL[(size_t)ks * 8192 + r0 + t];
    linv[t] = 1.f / l;
  }
  __syncthreads();

#pragma unroll
  for (int i = 0; i < 4; ++i) {
    int it = t + 256 * i;
    int row = it >> 4, g = it & 15;
    float a[8] = {0.f, 0.f, 0.f, 0.f, 0.f, 0.f, 0.f, 0.f};
#pragma unroll
    for (int ks = 0; ks < ATT_KSPLIT; ++ks) {
      uint4 u = *(const uint4*)(partO + ((size_t)ks * 8192 + r0 + row) * 128 + g * 8);
      const unsigned* uw = (const unsigned*)&u;
#pragma unroll
      for (int q = 0; q < 4; ++q) {
        a[2 * q] += bf2f(uw[q] & 0xffffu);
        a[2 * q + 1] += bf2f(uw[q] >> 16);
      }
    }
    float s = linv[row];
    uint4 pk;
    pk.x = f2bf(a[0] * s) | (f2bf(a[1] * s) << 16);
    pk.y = f2bf(a[2] * s) | (f2bf(a[3] * s) << 16);
    pk.z = f2bf(a[4] * s) | (f2bf(a[5] * s) << 16);
    pk.w = f2bf(a[6] * s) | (f2bf(a[7] * s) << 16);
    *(uint4*)&Al[row * 136 + g * 8] = pk;
  }
  __syncthreads();

  const int w = t >> 6, lane = t & 63, lg = lane >> 4, lc = lane & 15;
  const int mw = w & 1, nw = w >> 1;
  f32x4 acc[2][4];
#pragma unroll
  for (int m = 0; m < 2; ++m)
#pragma unroll
    for (int n = 0; n < 4; ++n)
#pragma unroll
      for (int r = 0; r < 4; ++r) acc[m][n][r] = 0.f;
  const unsigned short* wb =
      wf + (size_t)57 * 16384 + (size_t)(nw * 4) * 2048 + lane * 8;
#pragma unroll
  for (int k = 0; k < 4; ++k) {
    bf16x8 a0 = *(const bf16x8*)&Al[(mw * 32 + lc) * 136 + k * 32 + lg * 8];
    bf16x8 a1 = *(const bf16x8*)&Al[(mw * 32 + 16 + lc) * 136 + k * 32 + lg * 8];
#pragma unroll
    for (int n = 0; n < 4; ++n) {
      bf16x8 bfr = *(const bf16x8*)(wb + n * 2048 + k * 512);
      acc[0][n] = __builtin_amdgcn_mfma_f32_16x16x32_bf16(a0, bfr, acc[0][n], 0, 0, 0);
      acc[1][n] = __builtin_amdgcn_mfma_f32_16x16x32_bf16(a1, bfr, acc[1][n], 0, 0, 0);
    }
  }
#pragma unroll
  for (int n = 0; n < 4; ++n) {
    int col = nw * 64 + n * 16 + lc;
    float bb = bias[col];
#pragma unroll
    for (int m = 0; m < 2; ++m)
#pragma unroll
      for (int r = 0; r < 4; ++r) {
        int row = r0 + mw * 32 + m * 16 + lg * 4 + r;
        float v = acc[m][n][r] + bb;
        wy[(size_t)row * 128 + col] = v;
        wyb[(size_t)row * 128 + col] = (unsigned short)f2bf(v);
      }
  }
}

// ---------------------------------------------------------------- 3x3 reflect conv (bf16 MFMA)
// Block = 32 px x 64 co; 4 waves. Weights fragment-major from global -> regs.
// AFFINE: reduce IN-stat partials (part_in) in prologue, apply relu(a*v+b) in staging.
// Epilogue: bf16 out + transposed per-channel stat partials (part_out).
template <bool AFFINE>
__global__ __launch_bounds__(256) void k_conv(
    const unsigned short* __restrict__ act, const unsigned short* __restrict__ wf,
    const float* __restrict__ bias, const float* __restrict__ part_in,
    const float* __restrict__ gamma, const float* __restrict__ beta,
    unsigned short* __restrict__ outc, float* __restrict__ part_out) {
  __shared__ unsigned short Alds[3][34 * 136];
  __shared__ float red[256];
  __shared__ float Aff[2][128];

  const int t = threadIdx.x, bx = blockIdx.x;
  const int ch = bx & 1, xh = (bx >> 1) & 1, y = (bx >> 2) & 63, b = bx >> 8;
  const int w = t >> 6, lane = t & 63, lg = lane >> 4, lc = lane & 15;
  const int x0 = xh * 32;
  const int coT = ch * 4 + w;

  if constexpr (AFFINE) {
    const float4* p = (const float4*)(part_in + ((size_t)b * 256 + t) * 128);
    float s0 = 0.f, s1 = 0.f, s2 = 0.f, s3 = 0.f;
#pragma unroll 8
    for (int k = 0; k < 32; ++k) {
      float4 v = p[k];
      s0 += v.x; s1 += v.y; s2 += v.z; s3 += v.w;
    }
    red[t] = (s0 + s1) + (s2 + s3);
    __syncthreads();
    if (t < 128) {
      float mean = red[2 * t] * (1.f / 4096.f);
      float var = red[2 * t + 1] * (1.f / 4096.f) - mean * mean;
      float a = gamma[t] * rsqrtf(var + 1e-3f);
      Aff[0][t] = a;
      Aff[1][t] = beta[t] - mean * a;
    }
    __syncthreads();
  }

  const unsigned short* actB = act + (size_t)b * NT * CH;
#pragma unroll
  for (int i = 0; i < 7; ++i) {
    int it = t + 256 * i;
    if (it < 1632) {
      int r = it / 544, rem = it - r * 544;
      int px = rem >> 4, g = rem & 15;
      int sy = y - 1 + r;
      sy = sy < 0 ? 1 : (sy > 63 ? 62 : sy);
      int sx = x0 - 1 + px;
      sx = sx < 0 ? 1 : (sx > 63 ? 62 : sx);
      uint4 v = *(const uint4*)(actB + (size_t)(sy * 64 + sx) * CH + g * 8);
      if constexpr (AFFINE) {
        int c0 = g * 8;
        unsigned* vw = (unsigned*)&v;
#pragma unroll
        for (int q = 0; q < 4; ++q) {
          float v0 = bf2f(vw[q] & 0xffffu), v1 = bf2f(vw[q] >> 16);
          v0 = fmaxf(0.f, fmaf(Aff[0][c0 + 2 * q], v0, Aff[1][c0 + 2 * q]));
          v1 = fmaxf(0.f, fmaf(Aff[0][c0 + 2 * q + 1], v1, Aff[1][c0 + 2 * q + 1]));
          vw[q] = f2bf(v0) | (f2bf(v1) << 16);
        }
      }
      *(uint4*)&Alds[r][px * 136 + g * 8] = v;
    }
  }
  __syncthreads();

  f32x4 acc[2];
#pragma unroll
  for (int m = 0; m < 2; ++m)
#pragma unroll
    for (int r = 0; r < 4; ++r) acc[m][r] = 0.f;

  const unsigned short* wbase = wf + (size_t)coT * 2048 + lane * 8;
  bf16x8 wc[4], wn[4];
#pragma unroll
  for (int k = 0; k < 4; ++k) wc[k] = *(const bf16x8*)(wbase + k * 512);
#pragma unroll
  for (int tap = 0; tap < 9; ++tap) {
    const int dy = tap / 3, dx = tap - dy * 3;
    if (tap < 8) {
#pragma unroll
      for (int k = 0; k < 4; ++k)
        wn[k] = *(const bf16x8*)(wbase + (size_t)(tap + 1) * 16384 + k * 512);
    }
#pragma unroll
    for (int k = 0; k < 4; ++k) {
      bf16x8 a0 = *(const bf16x8*)&Alds[dy][(dx + lc) * 136 + k * 32 + lg * 8];
      bf16x8 a1 = *(const bf16x8*)&Alds[dy][(dx + 16 + lc) * 136 + k * 32 + lg * 8];
      acc[0] = __builtin_amdgcn_mfma_f32_16x16x32_bf16(a0, wc[k], acc[0], 0, 0, 0);
      acc[1] = __builtin_amdgcn_mfma_f32_16x16x32_bf16(a1, wc[k], acc[1], 0, 0, 0);
    }
#pragma unroll
    for (int k = 0; k < 4; ++k) wc[k] = wn[k];
  }

  const int col = coT * 16 + lc;
  const float bs = bias[col];
  float sum = 0.f, sq = 0.f;
  unsigned short* outB = outc + (size_t)(b * NT + y * 64 + x0) * CH;
#pragma unroll
  for (int m = 0; m < 2; ++m)
#pragma unroll
    for (int r = 0; r < 4; ++r) {
      float v = acc[m][r] + bs;
      int px = m * 16 + lg * 4 + r;
      outB[(size_t)px * CH + col] = (unsigned short)f2bf(v);
      sum += v;
      sq = fmaf(v, v, sq);
    }
  sum += __shfl_xor(sum, 16);
  sum += __shfl_xor(sum, 32);
  sq += __shfl_xor(sq, 16);
  sq += __shfl_xor(sq, 32);
  if (lg == 0) {
    const int pg = y * 2 + xh;
    part_out[((size_t)(b * 128 + col) * 2 + 0) * 128 + pg] = sum;
    part_out[((size_t)(b * 128 + col) * 2 + 1) * 128 + pg] = sq;
  }
}

// ---------------------------------------------------------------- residual (+fused stats reduce, +final blend)
// wy += IN(c2). FINAL: out = m*x + (1-m)*wy (skip wy/wyb stores). Else also emit bf16 wyb.
template <bool FINAL>
__global__ __launch_bounds__(256) void k_residual(
    const unsigned short* __restrict__ c2v, const float* __restrict__ part_in,
    const float* __restrict__ gamma, const float* __restrict__ beta,
    float* __restrict__ wy, unsigned short* __restrict__ wyb,
    const float* __restrict__ x, const float* __restrict__ mask,
    float* __restrict__ out) {
  __shared__ float red[256];
  __shared__ float AffA[128];
  __shared__ float AffB[128];
  const int t = threadIdx.x, bx = blockIdx.x;
  const int b = bx >> 8;

  {
    const float4* p = (const float4*)(part_in + ((size_t)b * 256 + t) * 128);
    float s0 = 0.f, s1 = 0.f, s2 = 0.f, s3 = 0.f;
#pragma unroll 8
    for (int k = 0; k < 32; ++k) {
      float4 v = p[k];
      s0 += v.x; s1 += v.y; s2 += v.z; s3 += v.w;
    }
    red[t] = (s0 + s1) + (s2 + s3);
  }
  __syncthreads();
  if (t < 128) {
    float mean = red[2 * t] * (1.f / 4096.f);
    float var = red[2 * t + 1] * (1.f / 4096.f) - mean * mean;
    float a = gamma[t] * rsqrtf(var + 1e-3f);
    AffA[t] = a;
    AffB[t] = beta[t] - mean * a;
  }
  __syncthreads();

  const int idx = bx * 256 + t;
  const int g = idx & 15;
  const int pixel = idx >> 4;
  const int c0 = g * 8;
  uint4 v = *(const uint4*)(c2v + (size_t)pixel * CH + c0);
  float* wp_ = wy + (size_t)pixel * CH + c0;
  float4 w0 = *(float4*)wp_, w1 = *(float4*)(wp_ + 4);
  float wv[8] = {w0.x, w0.y, w0.z, w0.w, w1.x, w1.y, w1.z, w1.w};
  const unsigned* vw = (const unsigned*)&v;
  float o[8];
#pragma unroll
  for (int q = 0; q < 8; ++q) {
    float cv = bf2f((q & 1) ? (vw[q >> 1] >> 16) : (vw[q >> 1] & 0xffffu));
    o[q] = wv[q] + fmaf(AffA[c0 + q], cv, AffB[c0 + q]);
  }
  if constexpr (FINAL) {
    const float m = maskval(mask[pixel]);
    const float* xp = x + (size_t)pixel * CH + c0;
    float4 x0 = *(const float4*)xp, x1 = *(const float4*)(xp + 4);
    float xv[8] = {x0.x, x0.y, x0.z, x0.w, x1.x, x1.y, x1.z, x1.w};
    float* op = out + (size_t)pixel * CH + c0;
    float r[8];
#pragma unroll
    for (int q = 0; q < 8; ++q) r[q] = m * xv[q] + (1.f - m) * o[q];
    *(float4*)op = make_float4(r[0], r[1], r[2], r[3]);
    *(float4*)(op + 4) = make_float4(r[4], r[5], r[6], r[7]);
  } else {
    *(float4*)wp_ = make_float4(o[0], o[1], o[2], o[3]);
    *(float4*)(wp_ + 4) = make_float4(o[4], o[5], o[6], o[7]);
    uint4 pk;
    pk.x = f2bf(o[0]) | (f2bf(o[1]) << 16);
    pk.y = f2bf(o[2]) | (f2bf(o[3]) << 16);
    pk.z = f2bf(o[4]) | (f2bf(o[5]) << 16);
    pk.w = f2bf(o[6]) | (f2bf(o[7]) << 16);
    *(uint4*)(wyb + (size_t)pixel * CH + c0) = pk;
  }
}

// ================================================================ launch
extern "C" void kernel_launch(void* const* d_in, const int* in_sizes, int n_in,
                              void* d_out, int out_size, void* d_ws, size_t ws_size,
                              hipStream_t stream) {
  (void)in_sizes; (void)n_in; (void)out_size; (void)ws_size;
  const float* x    = (const float*)d_in[0];
  const float* mask = (const float*)d_in[1];
  const float* wg   = (const float*)d_in[2];
  const float* bg   = (const float*)d_in[3];
  const float* wt   = (const float*)d_in[4];
  const float* bt   = (const float*)d_in[5];
  const float* wp   = (const float*)d_in[6];
  const float* bp   = (const float*)d_in[7];
  const float* ww   = (const float*)d_in[8];
  const float* bw   = (const float*)d_in[9];
  const float* rw1  = (const float*)d_in[10];
  const float* rb1  = (const float*)d_in[11];
  const float* rg1  = (const float*)d_in[12];
  const float* rbe1 = (const float*)d_in[13];
  const float* rw2  = (const float*)d_in[14];
  const float* rb2  = (const float*)d_in[15];
  const float* rg2  = (const float*)d_in[16];
  const float* rbe2 = (const float*)d_in[17];
  float* out = (float*)d_out;

  char* W = (char*)d_ws;
  unsigned short* wfrag = (unsigned short*)W;                     // 58*32 KB = 1.81 MB
  char* base = W + 2097152;
  unsigned short* thb   = (unsigned short*)(base);                // 2 MB
  unsigned short* phb   = (unsigned short*)(base + 2097152);      // 2 MB
  unsigned short* vtb   = (unsigned short*)(base + 2 * 2097152);  // 2 MB
  float*          partL = (float*)(base + 3 * 2097152);           // 256 KB
  unsigned short* partO = (unsigned short*)(base + 3 * 2097152 + 262144);  // 16 MB
  // aliases over dead regions (all consumers run after producers' regions die)
  float*          wy    = (float*)(base);                          // 4 MB over thb+phb
  unsigned short* wyb   = (unsigned short*)(base + 2 * 2097152);   // 2 MB over vtb
  unsigned short* c1    = partO;                                   // 2 MB
  unsigned short* c2    = (unsigned short*)((char*)partO + 2097152);       // 2 MB
  float*          partA = (float*)((char*)partO + 2 * 2097152);    // 256 KB
  float*          partB = (float*)((char*)partO + 2 * 2097152 + 262144);   // 256 KB

  k_prepw<<<58, 256, 0, stream>>>(rw1, rw2, wt, wp, wg, ww, wfrag);
  k_proj3<<<128, 256, 0, stream>>>(x, mask, wfrag, bt, bp, bg, thb, phb, vtb);
  k_attn<<<512, 256, 0, stream>>>(thb, phb, vtb, partO, partL);
  k_gemmW<<<128, 256, 0, stream>>>(partO, partL, wfrag, bw, wy, wyb);

  for (int i = 0; i < 3; ++i) {
    const unsigned short* wf1 = wfrag + (size_t)(2 * i) * 9 * 16384;
    const unsigned short* wf2 = wfrag + (size_t)(2 * i + 1) * 9 * 16384;
    k_conv<false><<<512, 256, 0, stream>>>(wyb, wf1, rb1 + i * 128, nullptr,
                                           nullptr, nullptr, c1, partA);
    k_conv<true><<<512, 256, 0, stream>>>(c1, wf2, rb2 + i * 128, partA,
                                          rg1 + i * 128, rbe1 + i * 128, c2, partB);
    if (i < 2) {
      k_residual<false><<<512, 256, 0, stream>>>(c2, partB, rg2 + i * 128,
                                                 rbe2 + i * 128, wy, wyb,
                                                 nullptr, nullptr, nullptr);
    } else {
      k_residual<true><<<512, 256, 0, stream>>>(c2, partB, rg2 + i * 128,
                                                rbe2 + i * 128, wy, nullptr,
                                                x, mask, out);
    }
  }
}